// Round 11
// baseline (398.298 us; speedup 1.0000x reference)
//
#include <hip/hip_runtime.h>

// ---------------------------------------------------------------------------
// TransformerBlock on MI355X (gfx950), round 11:
//  - 2D supertile (8by x 4bx) block ordering under the bijective XCD chunk
//    swizzle for qkv/sgu/wo/final GEMMs: per-XCD working set fits one L2
//    (weights reused 8x, A 4x from cache) -> lower load latency.
//  - attention: KVBLK=128 staging (two 64-wide subtiles per buffer, 64KB
//    LDS, still 2 blocks/CU) -> half the barrier/vmcnt drains.
//  - GEMM core: round-8 proven (BK=64, dbuf, depth-1 counted vmcnt).
// ---------------------------------------------------------------------------

typedef unsigned short u16;
typedef __attribute__((ext_vector_type(8))) short bh8;   // 8 x bf16
typedef __attribute__((ext_vector_type(4))) float fv4;
typedef __attribute__((ext_vector_type(4))) unsigned uv4;
typedef __attribute__((ext_vector_type(2))) int iv2;

#define LOG2E 1.4426950408889634f
#define MAX_TILES 71

__device__ __forceinline__ float b2f(u16 u) {
  return __builtin_bit_cast(float, ((unsigned)u) << 16);
}
__device__ __forceinline__ u16 f2b(float f) {
  unsigned x = __builtin_bit_cast(unsigned, f);
  return (u16)((x + 0x7fffu + ((x >> 16) & 1u)) >> 16);  // RNE
}
__device__ __forceinline__ fv4 mfma16(bh8 a, bh8 b, fv4 c) {
  return __builtin_amdgcn_mfma_f32_16x16x32_bf16(a, b, c, 0, 0, 0);
}
__device__ __forceinline__ unsigned cvtpk(float lo, float hi) {
  unsigned r;
  asm("v_cvt_pk_bf16_f32 %0, %1, %2" : "=v"(r) : "v"(lo), "v"(hi));
  return r;
}

// Bijective XCD-chunk swizzle (m204): XCD k gets a contiguous run of the
// logical block order.
__device__ __forceinline__ int xcd_swizzle1d(int flat, int nwg) {
  int q = nwg >> 3, r = nwg & 7;
  int xcd = flat & 7, idx = flat >> 3;
  return (xcd < r ? xcd * (q + 1) : r * (q + 1) + (xcd - r) * q) + idx;
}

#define GLD16(g, l)                                                        \
  __builtin_amdgcn_global_load_lds(                                        \
      (const __attribute__((address_space(1))) void*)(g),                  \
      (__attribute__((address_space(3))) void*)(l), 16, 0, 0)

// Read one MFMA fragment (16B) from a [rows][64] bf16 LDS tile whose rows are
// 128B and whose 16B blocks are XOR-swizzled by (row&7).
__device__ __forceinline__ bh8 lds_frag(const u16* base, int row, int b8) {
  int off = row * 128 + ((b8 * 16) ^ ((row & 7) << 4));
  return *(const bh8*)((const char*)base + off);
}

// ---------------------------------------------------------------------------
// Shared GEMM body: C[M,N] = A[M,K] (bf16) @ B[N,K]^T (bf16), f32 accumulate.
// TM: A-tile rows (128 or 64). B-tile is always 128 cols.
// MODE 0: Cb = bf16(gemm)
// MODE 1: Cf = add1 + gemm
// MODE 6: compact-A grouped MoE (w2): lda via M; Cb = bf16(gemm + bias_e)
//         (TM=64: by encodes tile*2+half)
// MODE 7: interleaved silu (shared expert): Cb[.,N/2] = silu(g)*u
// MODE 8: gather-A grouped MoE w13, interleaved silu + biases
// MODE 9: final: Cf = add1 + gemm + w0*eo[r0] + w1*eo[r1]
// K-loop: BK=64, dbuf, depth-1 prefetch, counted vmcnt, raw barriers.
// ---------------------------------------------------------------------------
template <int MODE, int TM>
__device__ __forceinline__ void gemm_body(
    u16* AsB, u16* BsB, int bx, int by, const u16* __restrict__ A,
    const u16* __restrict__ B, int M, int N, int K, u16* __restrict__ Cb,
    float* __restrict__ Cf, const float* __restrict__ add1,
    const float* __restrict__ add2, const float* __restrict__ bias,
    const int* __restrict__ tmeta, const int* __restrict__ etok) {
  constexpr int MR = TM / 32;  // M-frags per wave: 128->4, 64->2
  const int lane = threadIdx.x & 63;
  const int wid = threadIdx.x >> 6;
  const int wr = wid >> 1, wc = wid & 1;
  const int n0 = bx * 128;
  const int rr = lane >> 3;
  const int b8s = (lane & 7) ^ rr;
  const int ldA = (MODE == 6) ? M : K;

  int m0 = 0, e = 0, m0l = 0, cnt = 0, row0 = 0;
  const u16* Bp = B;
  if constexpr (MODE == 6 || MODE == 8) {
    int tile = by, half = 0;
    if constexpr (MODE == 6 && TM == 64) {
      tile = by >> 1;
      half = by & 1;
    }
    if (tile >= tmeta[0]) return;
    e = tmeta[16 + tile * 4];
    m0l = tmeta[17 + tile * 4];
    cnt = tmeta[18 + tile * 4];
    row0 = tmeta[19 + tile * 4] + half * 64;
    Bp = B + (size_t)e * N * K;
  } else {
    m0 = by * TM;
  }

  const u16* Arow[MR];
  const u16* Brow[4];
#pragma unroll
  for (int i = 0; i < MR; ++i) {
    int c = wid * MR + i;
    int row = c * 8 + rr;
    if constexpr (MODE == 8) {
      int li = m0l + row;
      li = li < cnt ? li : cnt - 1;
      int tok = etok[e * 4096 + li];
      Arow[i] = A + (size_t)tok * ldA + b8s * 8;
    } else if constexpr (MODE == 6) {
      Arow[i] = A + (size_t)(row0 + row) * ldA + b8s * 8;
    } else {
      Arow[i] = A + (size_t)(m0 + row) * ldA + b8s * 8;
    }
  }
#pragma unroll
  for (int i = 0; i < 4; ++i)
    Brow[i] = Bp + (size_t)(n0 + (wid * 4 + i) * 8 + rr) * K + b8s * 8;

  fv4 acc[MR][4] = {};
  const int nt = K >> 6;

  // prologue: stage tile 0 into buffer 0
#pragma unroll
  for (int i = 0; i < MR; ++i)
    GLD16(Arow[i], &AsB[(wid * MR + i) * 512]);
#pragma unroll
  for (int i = 0; i < 4; ++i)
    GLD16(Brow[i], &BsB[(wid * 4 + i) * 512]);

  for (int t = 0; t < nt; ++t) {
    const int cur = t & 1;
    u16* Asc = AsB + cur * (TM * 64);
    u16* Bsc = BsB + cur * (128 * 64);
    if (t + 1 < nt) {
      const int k0 = (t + 1) * 64;
      u16* Asn = AsB + (cur ^ 1) * (TM * 64);
      u16* Bsn = BsB + (cur ^ 1) * (128 * 64);
#pragma unroll
      for (int i = 0; i < MR; ++i)
        GLD16(Arow[i] + k0, &Asn[(wid * MR + i) * 512]);
#pragma unroll
      for (int i = 0; i < 4; ++i)
        GLD16(Brow[i] + k0, &Bsn[(wid * 4 + i) * 512]);
      // wait only for the OLDEST (cur-tile) loads; next-tile stays in flight
      if constexpr (MR == 4)
        asm volatile("s_waitcnt vmcnt(8)" ::: "memory");
      else
        asm volatile("s_waitcnt vmcnt(6)" ::: "memory");
    } else {
      asm volatile("s_waitcnt vmcnt(0)" ::: "memory");
    }
    __builtin_amdgcn_s_barrier();          // buf[cur] visible to all waves
    __builtin_amdgcn_sched_barrier(0);     // pin ds_reads below barrier

#pragma unroll
    for (int ks = 0; ks < 2; ++ks) {
      int b8 = ks * 4 + (lane >> 4);
      bh8 af[MR], bf[4];
#pragma unroll
      for (int mi = 0; mi < MR; ++mi)
        af[mi] = lds_frag(Asc, wr * (16 * MR) + mi * 16 + (lane & 15), b8);
#pragma unroll
      for (int ni = 0; ni < 4; ++ni)
        bf[ni] = lds_frag(Bsc, wc * 64 + ni * 16 + (lane & 15), b8);
      __builtin_amdgcn_s_setprio(1);
#pragma unroll
      for (int mi = 0; mi < MR; ++mi)
#pragma unroll
        for (int ni = 0; ni < 4; ++ni)
          acc[mi][ni] = mfma16(af[mi], bf[ni], acc[mi][ni]);
      __builtin_amdgcn_s_setprio(0);
    }
    __builtin_amdgcn_sched_barrier(0);     // pin reads above barrier
    __builtin_amdgcn_s_barrier();          // all waves done reading buf[cur]
    __builtin_amdgcn_sched_barrier(0);     // pin next stage below barrier
  }

  const int rbase = (MODE == 6 || MODE == 8) ? row0 : m0;
  const int r0b = rbase + wr * (16 * MR) + (lane >> 4) * 4;
  const int c0b = n0 + wc * 64 + (lane & 15);

  if constexpr (MODE == 7 || MODE == 8) {
    const int OUTN = N >> 1;
    const int colb = (n0 >> 1) + wc * 32;
    const float* bb1 = nullptr;
    const float* bb3 = nullptr;
    if constexpr (MODE == 8) {
      bb1 = add1 + (size_t)e * OUTN;
      bb3 = add2 + (size_t)e * OUTN;
    }
#pragma unroll
    for (int mi = 0; mi < MR; ++mi) {
#pragma unroll
      for (int ni = 0; ni < 2; ++ni) {
        int c = colb + ni * 16 + (lane & 15);
#pragma unroll
        for (int r = 0; r < 4; ++r) {
          int row = r0b + mi * 16 + r;
          float xg = acc[mi][ni][r];
          float yu = acc[mi][ni + 2][r];
          if constexpr (MODE == 8) {
            xg += bb1[c];
            yu += bb3[c];
          }
          float s = xg / (1.f + __expf(-xg));
          Cb[(size_t)row * OUTN + c] = f2b(s * yu);
        }
      }
    }
  } else if constexpr (MODE == 9) {
#pragma unroll
    for (int mi = 0; mi < MR; ++mi) {
#pragma unroll
      for (int r = 0; r < 4; ++r) {
        int row = r0b + mi * 16 + r;
        int g0 = tmeta[2 * row], g1 = tmeta[2 * row + 1];
        float w0 = bias[2 * row], w1 = bias[2 * row + 1];
        const u16* e0p = Cb + (size_t)g0 * 1024;
        const u16* e1p = Cb + (size_t)g1 * 1024;
#pragma unroll
        for (int ni = 0; ni < 4; ++ni) {
          int c = c0b + ni * 16;
          size_t idx = (size_t)row * N + c;
          Cf[idx] = add1[idx] + acc[mi][ni][r] + w0 * b2f(e0p[c]) +
                    w1 * b2f(e1p[c]);
        }
      }
    }
  } else {
    const float* bb = nullptr;
    if constexpr (MODE == 6) bb = bias + (size_t)e * N;
#pragma unroll
    for (int mi = 0; mi < MR; ++mi) {
#pragma unroll
      for (int ni = 0; ni < 4; ++ni) {
        int c = c0b + ni * 16;
#pragma unroll
        for (int r = 0; r < 4; ++r) {
          int row = r0b + mi * 16 + r;
          size_t idx = (size_t)row * N + c;
          float v = acc[mi][ni][r];
          if constexpr (MODE == 0) Cb[idx] = f2b(v);
          else if constexpr (MODE == 1) Cf[idx] = add1[idx] + v;
          else Cb[idx] = f2b(v + bb[c]);
        }
      }
    }
  }
}

// STILE=1: decode the (XCD-chunked) flat index as 8by x 4bx supertiles so
// each XCD's contiguous run has a 2D footprint that fits its L2.
// Requires gridDim.x % 4 == 0 and gridDim.y % 8 == 0.
template <int MODE, int TM = 128, int STILE = 0>
__global__ __launch_bounds__(256) void gemm_bt(
    const u16* __restrict__ A, const u16* __restrict__ B, int M, int N, int K,
    u16* __restrict__ Cb, float* __restrict__ Cf,
    const float* __restrict__ add1, const float* __restrict__ add2,
    const float* __restrict__ bias, const int* __restrict__ tmeta,
    const int* __restrict__ etok) {
  __shared__ u16 As[2][TM * 64];
  __shared__ u16 Bs[2][128 * 64];
  const int gx = gridDim.x;
  int flat = (int)blockIdx.y * gx + (int)blockIdx.x;
  flat = xcd_swizzle1d(flat, gx * (int)gridDim.y);
  int bx, by;
  if constexpr (STILE) {
    int SX = gx >> 2;
    int sidx = flat >> 5, within = flat & 31;
    int sy = sidx / SX, sx = sidx - sy * SX;
    by = sy * 8 + (within >> 2);
    bx = sx * 4 + (within & 3);
  } else {
    by = flat / gx;
    bx = flat - by * gx;
  }
  gemm_body<MODE, TM>(&As[0][0], &Bs[0][0], bx, by, A, B, M, N, K, Cb, Cf,
                      add1, add2, bias, tmeta, etok);
}

// Merged shared-expert (MODE 7, supertiled 32x32) + MoE w13 (MODE 8).
__global__ __launch_bounds__(256) void gemm_sgu_w13(
    const u16* __restrict__ hf, const u16* __restrict__ sgu_w,
    u16* __restrict__ hs, const u16* __restrict__ w13_w,
    u16* __restrict__ a13, const float* __restrict__ b1,
    const float* __restrict__ b3, const int* __restrict__ meta,
    const int* __restrict__ etok) {
  __shared__ u16 As[2][128 * 64];
  __shared__ u16 Bs[2][128 * 64];
  const int nwg = 1024 + 16 * MAX_TILES;
  int flat = xcd_swizzle1d((int)blockIdx.x, nwg);
  if (flat < 1024) {
    // supertile decode: gx=32 (SX=8), gy=32
    int sidx = flat >> 5, within = flat & 31;
    int sy = sidx >> 3, sx = sidx & 7;
    int by = sy * 8 + (within >> 2);
    int bx = sx * 4 + (within & 3);
    gemm_body<7, 128>(&As[0][0], &Bs[0][0], bx, by, hf, sgu_w, 4096, 4096,
                      1024, hs, nullptr, nullptr, nullptr, nullptr, nullptr,
                      nullptr);
  } else {
    int idx = flat - 1024;
    int by = idx >> 4, bx = idx & 15;
    gemm_body<8, 128>(&As[0][0], &Bs[0][0], bx, by, hf, w13_w, 4096, 2048,
                      1024, a13, nullptr, b1, b3, nullptr, meta, etok);
  }
}

// ---------------------------------------------------------------------------
// RMSNorm: f32 [T,1024] -> bf16 [T,1024], one block per token.
// ---------------------------------------------------------------------------
__global__ __launch_bounds__(256) void rmsnorm_bf16(
    const float* __restrict__ x, const float* __restrict__ w,
    u16* __restrict__ out) {
  int t = blockIdx.x;
  const float* xr = x + (size_t)t * 1024;
  fv4 v = *(const fv4*)(xr + threadIdx.x * 4);
  float ss = v[0] * v[0] + v[1] * v[1] + v[2] * v[2] + v[3] * v[3];
#pragma unroll
  for (int off = 1; off < 64; off <<= 1) ss += __shfl_xor(ss, off);
  __shared__ float red[4];
  int lane = threadIdx.x & 63, wid = threadIdx.x >> 6;
  if (lane == 0) red[wid] = ss;
  __syncthreads();
  float inv = rsqrtf((red[0] + red[1] + red[2] + red[3]) * (1.0f / 1024.f) + 1e-6f);
  u16* op = out + (size_t)t * 1024 + threadIdx.x * 4;
  const float* wp = w + threadIdx.x * 4;
#pragma unroll
  for (int i = 0; i < 4; ++i) op[i] = f2b(v[i] * inv * wp[i]);
}

// ---------------------------------------------------------------------------
// RoPE + repack from fused qkv [T,3072]:
//   q,k -> rotated [B,NH,S,64]; v -> vt [B,NH,64,S] (transposed AND column-
//   permuted per 64-block: physical group pg=4ks+g holds logical j
//   {16ks+4g+r, 16ks+32+4g+r}).  Grid: (S/64, B, NH/4).
// ---------------------------------------------------------------------------
__global__ __launch_bounds__(256) void rope_repack(
    const u16* __restrict__ qkv, const float* __restrict__ fc,
    const float* __restrict__ fs, u16* __restrict__ qr, u16* __restrict__ kr,
    u16* __restrict__ vt, int S) {
  __shared__ u16 tile[64][65];
  const int s0 = blockIdx.x * 64;
  const int b = blockIdx.y;
  const int h0 = blockIdx.z * 4;
#pragma unroll 4
  for (int it = 0; it < 32; ++it) {
    int idx = threadIdx.x + it * 256;
    int tl = idx >> 7, rem = idx & 127;
    int h = h0 + (rem >> 5), i = rem & 31;
    int s = s0 + tl;
    float c = fc[s * 32 + i], sn = fs[s * 32 + i];
    size_t src = ((size_t)(b * S + s)) * 3072 + h * 64 + 2 * i;
    size_t dst = ((size_t)((b * 16 + h) * S + s)) * 64 + 2 * i;
    float a0 = b2f(qkv[src]), a1 = b2f(qkv[src + 1]);
    qr[dst] = f2b(a0 * c - a1 * sn);
    qr[dst + 1] = f2b(a0 * sn + a1 * c);
    float b0 = b2f(qkv[src + 1024]), b1 = b2f(qkv[src + 1025]);
    kr[dst] = f2b(b0 * c - b1 * sn);
    kr[dst + 1] = f2b(b0 * sn + b1 * c);
  }
  for (int hh = 0; hh < 4; ++hh) {
    int h = h0 + hh;
    __syncthreads();
    for (int cc = threadIdx.x; cc < 512; cc += 256) {
      int tl = cc >> 3, d8 = cc & 7;
      bh8 val = *(const bh8*)(qkv + ((size_t)(b * S + s0 + tl)) * 3072 + 2048 +
                              h * 64 + d8 * 8);
#pragma unroll
      for (int j = 0; j < 8; ++j) tile[tl][d8 * 8 + j] = (u16)val[j];
    }
    __syncthreads();
    for (int cc = threadIdx.x; cc < 512; cc += 256) {
      int d = cc >> 3, pg = cc & 7;
      int sbase = 16 * (pg >> 2) + 4 * (pg & 3);
      bh8 o;
#pragma unroll
      for (int j = 0; j < 8; ++j)
        o[j] = (short)tile[sbase + (j & 3) + ((j >> 2) << 5)][d];
      *(bh8*)(vt + ((size_t)((b * 16 + h) * 64 + d)) * S + s0 + pg * 8) = o;
    }
  }
}

// ---------------------------------------------------------------------------
// Flash attention (causal), paired q-tiles, KVBLK=128 staging (two 64-wide
// subtiles per buffer -> one barrier per 128 kv), hoisted shared K/V frags,
// MFMA row-sum, fma-folded scale, defer-max.
// Grid: (B*NH, nq/2). 4 waves x 16 q-rows.
// ---------------------------------------------------------------------------
__global__ __launch_bounds__(256) void attn_fwd(
    const u16* __restrict__ qr, const u16* __restrict__ kr,
    const u16* __restrict__ vt, u16* __restrict__ ob, int S, int NHc) {
  __shared__ u16 Ks[2][2][64 * 64];
  __shared__ u16 Vs[2][2][64 * 64];   // V^T subtiles, column-permuted
  const int lane = threadIdx.x & 63;
  const int wid = threadIdx.x >> 6;
  const int g = lane >> 4;
  const int l15 = lane & 15;
  const int bh = blockIdx.x;
  const int ia = blockIdx.y;
  const int nq = S / 64;
  const int qa0 = ia * 64;                 // light q-tile
  const int qb0 = (nq - 1 - ia) * 64;      // heavy q-tile
  const int b = bh / NHc, h = bh % NHc;
  const u16* qbase = qr + (size_t)bh * S * 64;
  const u16* kb = kr + (size_t)bh * S * 64;
  const u16* vb = vt + (size_t)bh * 64 * S;
  const float SC = 0.015625f * LOG2E;  // both ref scales, log2 domain
  const int rr = lane >> 3;
  const int b8s = (lane & 7) ^ rr;

  bh8 ONES;
#pragma unroll
  for (int j = 0; j < 8; ++j) ONES[j] = (short)0x3f80;  // bf16 1.0

  bh8 qfA[2], qfB[2];
  {
    const u16* qp = qbase + (size_t)(qa0 + wid * 16 + l15) * 64 + g * 8;
    qfA[0] = *(const bh8*)qp;
    qfA[1] = *(const bh8*)(qp + 32);
    qp = qbase + (size_t)(qb0 + wid * 16 + l15) * 64 + g * 8;
    qfB[0] = *(const bh8*)qp;
    qfB[1] = *(const bh8*)(qp + 32);
  }
  fv4 oaccA[4] = {}, oaccB[4] = {};
  fv4 lA = {}, lB = {};                // row-sums, C-layout (row = 4g+r)
  float mA = -1e30f, mB = -1e30f;
  const int nktB = nq - ia;            // 64-wide kv tiles for heavy q-tile
  const int nrounds = (nktB + 1) >> 1; // 128-wide staging rounds

  auto stage = [&](int buf, int j0, int nsub) {
    for (int s = 0; s < nsub; ++s) {
#pragma unroll
      for (int i = 0; i < 2; ++i) {
        int c = wid * 2 + i;
        int row = c * 8 + rr;
        GLD16(kb + (size_t)(j0 + s * 64 + row) * 64 + b8s * 8,
              &Ks[buf][s][c * 512]);
        GLD16(vb + (size_t)row * S + j0 + s * 64 + b8s * 8,
              &Vs[buf][s][c * 512]);
      }
    }
  };
  stage(0, 0, nktB > 1 ? 2 : 1);

  auto process = [&](const bh8 (&kf)[2][4], const bh8 (&vf)[2][4], int j0,
                     int q0x, bh8* qf, fv4* oacc, float& mrow, fv4& lrowC) {
    const int q_my = q0x + wid * 16 + l15;
    fv4 st[4] = {};
    __builtin_amdgcn_s_setprio(1);
#pragma unroll
    for (int ks = 0; ks < 2; ++ks)
#pragma unroll
      for (int jt = 0; jt < 4; ++jt)
        st[jt] = mfma16(kf[ks][jt], qf[ks], st[jt]);
    __builtin_amdgcn_s_setprio(0);

    // mask + max on RAW scores (SC > 0 so max commutes with the scale)
    float sr[4][4];
    float mloc = -1e30f;
    const int jb = j0 + 4 * g;
    if (j0 + 63 > q0x + wid * 16) {   // diagonal tile
#pragma unroll
      for (int jt = 0; jt < 4; ++jt)
#pragma unroll
        for (int r = 0; r < 4; ++r) {
          int j = jb + jt * 16 + r;
          float s = (j <= q_my) ? st[jt][r] : -1e30f;
          sr[jt][r] = s;
          mloc = fmaxf(mloc, s);
        }
    } else {                          // interior: fully visible
#pragma unroll
      for (int jt = 0; jt < 4; ++jt)
#pragma unroll
        for (int r = 0; r < 4; ++r) {
          sr[jt][r] = st[jt][r];
          mloc = fmaxf(mloc, st[jt][r]);
        }
    }
    mloc = fmaxf(mloc, __shfl_xor(mloc, 16));
    mloc = fmaxf(mloc, __shfl_xor(mloc, 32));
    mloc *= SC;                        // scaled row max (log2 domain)
    bool defer = __all(mloc <= mrow + 8.f);   // T13
    if (!defer) {
      float mnew = fmaxf(mrow, mloc);
      float sfac = exp2f(mrow - mnew);
      mrow = mnew;
      float sfC[4];
#pragma unroll
      for (int r = 0; r < 4; ++r) sfC[r] = __shfl(sfac, g * 4 + r);
#pragma unroll
      for (int dt = 0; dt < 4; ++dt)
#pragma unroll
        for (int r = 0; r < 4; ++r) oacc[dt][r] *= sfC[r];
#pragma unroll
      for (int r = 0; r < 4; ++r) lrowC[r] *= sfC[r];
    }
    float p[4][4];
#pragma unroll
    for (int jt = 0; jt < 4; ++jt)
#pragma unroll
      for (int r = 0; r < 4; ++r)
        p[jt][r] = exp2f(fmaf(sr[jt][r], SC, -mrow));

    // PV + row-sum via MFMA (pa slot (g,i) <-> logical j matching permuted V)
    __builtin_amdgcn_s_setprio(1);
    fv4 racc = {};
#pragma unroll
    for (int ks = 0; ks < 2; ++ks) {
      uv4 w;
      w[0] = cvtpk(p[ks][0], p[ks][1]);
      w[1] = cvtpk(p[ks][2], p[ks][3]);
      w[2] = cvtpk(p[ks + 2][0], p[ks + 2][1]);
      w[3] = cvtpk(p[ks + 2][2], p[ks + 2][3]);
      bh8 pa = __builtin_bit_cast(bh8, w);
      racc = mfma16(pa, ONES, racc);
#pragma unroll
      for (int dt = 0; dt < 4; ++dt)
        oacc[dt] = mfma16(pa, vf[ks][dt], oacc[dt]);
    }
    __builtin_amdgcn_s_setprio(0);
#pragma unroll
    for (int r = 0; r < 4; ++r) lrowC[r] += racc[r];
  };

  for (int rd = 0; rd < nrounds; ++rd) {
    __syncthreads();  // drains staging for buf[rd&1]; joins all waves
    int rem = nktB - (rd + 1) * 2;
    if (rem > 0) stage((rd + 1) & 1, (rd + 1) * 128, rem > 1 ? 2 : 1);
#pragma unroll
    for (int s = 0; s < 2; ++s) {
      int kt = rd * 2 + s;
      if (kt >= nktB) break;
      const int j0 = kt * 64;
      const u16* Kc = Ks[rd & 1][s];
      const u16* Vc = Vs[rd & 1][s];
      bh8 kf[2][4], vf[2][4];
#pragma unroll
      for (int ks = 0; ks < 2; ++ks) {
        int b8 = ks * 4 + g;
#pragma unroll
        for (int jt = 0; jt < 4; ++jt)
          kf[ks][jt] = lds_frag(Kc, jt * 16 + l15, b8);
#pragma unroll
        for (int dt = 0; dt < 4; ++dt)
          vf[ks][dt] = lds_frag(Vc, dt * 16 + l15, b8);
      }
      process(kf, vf, j0, qb0, qfB, oaccB, mB, lB);
      if (kt <= ia) process(kf, vf, j0, qa0, qfA, oaccA, mA, lA);
    }
  }

  auto wout = [&](fv4* oacc, fv4 lrowC, int q0x) {
#pragma unroll
    for (int dt = 0; dt < 4; ++dt)
#pragma unroll
      for (int r = 0; r < 4; ++r) {
        int row = q0x + wid * 16 + g * 4 + r;
        int col = dt * 16 + l15;
        ob[((size_t)b * S + row) * 1024 + h * 64 + col] =
            f2b(oacc[dt][r] / lrowC[r]);
      }
  };
  wout(oaccA, lA, qa0);
  wout(oaccB, lB, qb0);
}

// ---------------------------------------------------------------------------
// Gate + fused ffn-rmsnorm: computes top-2 AND writes hf_b = bf16(rmsnorm).
// ---------------------------------------------------------------------------
__global__ __launch_bounds__(256) void gate_topk(
    const float* __restrict__ x2, const float* __restrict__ nw,
    const float* __restrict__ gw, const float* __restrict__ gb,
    int* __restrict__ topk_e, float* __restrict__ topk_w,
    u16* __restrict__ hf) {
  int t = blockIdx.x * 4 + (threadIdx.x >> 6);
  int lane = threadIdx.x & 63;
  const float* xr = x2 + (size_t)t * 1024;
  float hv[16];
  float ss = 0.f;
#pragma unroll
  for (int i = 0; i < 4; ++i) {
    fv4 v = *(const fv4*)(xr + lane * 16 + i * 4);
#pragma unroll
    for (int j = 0; j < 4; ++j) {
      hv[i * 4 + j] = v[j];
      ss += v[j] * v[j];
    }
  }
#pragma unroll
  for (int off = 1; off < 64; off <<= 1) ss += __shfl_xor(ss, off);
  float inv = rsqrtf(ss * (1.0f / 1024.f) + 1e-6f);
  const fv4* nwp = (const fv4*)(nw + lane * 16);
#pragma unroll
  for (int i = 0; i < 4; ++i) {
    fv4 wv = nwp[i];
#pragma unroll
    for (int j = 0; j < 4; ++j) hv[i * 4 + j] *= inv * wv[j];
  }
  {  // fused rmsnorm output
    bh8 o0, o1;
#pragma unroll
    for (int j = 0; j < 8; ++j) {
      o0[j] = (short)f2b(hv[j]);
      o1[j] = (short)f2b(hv[8 + j]);
    }
    u16* hp = hf + (size_t)t * 1024 + lane * 16;
    *(bh8*)hp = o0;
    *(bh8*)(hp + 8) = o1;
  }
  float logit[8];
#pragma unroll
  for (int e = 0; e < 8; ++e) {
    const fv4* wp = (const fv4*)(gw + (size_t)e * 1024 + lane * 16);
    float s = 0.f;
#pragma unroll
    for (int i = 0; i < 4; ++i) {
      fv4 wv = wp[i];
#pragma unroll
      for (int j = 0; j < 4; ++j) s += hv[i * 4 + j] * wv[j];
    }
    logit[e] = s;
  }
#pragma unroll
  for (int off = 1; off < 64; off <<= 1)
#pragma unroll
    for (int e = 0; e < 8; ++e) logit[e] += __shfl_xor(logit[e], off);
  if (lane == 0) {
#pragma unroll
    for (int e = 0; e < 8; ++e) logit[e] += gb[e];
    float mx = logit[0];
#pragma unroll
    for (int e = 1; e < 8; ++e) mx = fmaxf(mx, logit[e]);
    float pe[8], se = 0.f;
#pragma unroll
    for (int e = 0; e < 8; ++e) { pe[e] = __expf(logit[e] - mx); se += pe[e]; }
    float rs = 1.f / se;
#pragma unroll
    for (int e = 0; e < 8; ++e) pe[e] *= rs;
    int i0 = 0;
    float b0 = pe[0];
#pragma unroll
    for (int e = 1; e < 8; ++e)
      if (pe[e] > b0) { b0 = pe[e]; i0 = e; }
    int i1 = -1;
    float b1v = -1.f;
#pragma unroll
    for (int e = 0; e < 8; ++e)
      if (e != i0 && pe[e] > b1v) { b1v = pe[e]; i1 = e; }
    topk_e[2 * t] = i0;
    topk_e[2 * t + 1] = i1;
    topk_w[2 * t] = b0;
    topk_w[2 * t + 1] = b1v;
  }
}

// One block, 8 waves: wave e ballot-ranks its tokens (deterministic order),
// thread 0 builds the padded tile map, then all threads fill rowid[2T]
// (compact row index of each token's two expert outputs).
__global__ __launch_bounds__(512) void route_tokens(
    const int* __restrict__ topk_e, int* __restrict__ pos_of,
    int* __restrict__ etok, int* __restrict__ meta, int* __restrict__ rowid,
    int T2) {
  __shared__ int scnt[8], sbase[8];
  const int e = threadIdx.x >> 6;
  const int lane = threadIdx.x & 63;
  int base = 0;
  for (int i0 = 0; i0 < T2; i0 += 128) {
    iv2 te = *(const iv2*)(topk_e + i0 + lane * 2);
    unsigned long long m0 = __ballot(te[0] == e);
    unsigned long long m1 = __ballot(te[1] == e);
    unsigned long long lt = (1ull << lane) - 1;
    int pre = __popcll(m0 & lt) + __popcll(m1 & lt);
    if (te[0] == e) {
      int pos = base + pre;
      etok[e * 4096 + pos] = (i0 >> 1) + lane;
      pos_of[i0 + lane * 2] = pos;
      ++pre;
    }
    if (te[1] == e) {
      int pos = base + pre;
      etok[e * 4096 + pos] = (i0 >> 1) + lane;
      pos_of[i0 + lane * 2 + 1] = pos;
    }
    base += __popcll(m0) + __popcll(m1);
  }
  if (lane == 0) scnt[e] = base;
  __syncthreads();
  if (threadIdx.x == 0) {
    int tt = 0, rb = 0;
#pragma unroll
    for (int e2 = 0; e2 < 8; ++e2) {
      sbase[e2] = rb;
      int c = scnt[e2];
      int nt = (c + 127) >> 7;
      for (int i = 0; i < nt; ++i) {
        meta[16 + tt * 4] = e2;
        meta[17 + tt * 4] = i * 128;
        meta[18 + tt * 4] = c;
        meta[19 + tt * 4] = rb + i * 128;
        ++tt;
      }
      rb += nt * 128;
    }
    meta[0] = tt;
  }
  __syncthreads();
  for (int i = threadIdx.x; i < T2; i += 512)
    rowid[i] = sbase[topk_e[i]] + pos_of[i];
}

__global__ __launch_bounds__(256) void f2b_convert(
    const float* __restrict__ src, u16* __restrict__ dst) {
  size_t i = ((size_t)blockIdx.x * 256 + threadIdx.x) * 8;
  fv4 a = *(const fv4*)(src + i);
  fv4 b = *(const fv4*)(src + i + 4);
  bh8 o;
#pragma unroll
  for (int j = 0; j < 4; ++j) o[j] = (short)f2b(a[j]);
#pragma unroll
  for (int j = 0; j < 4; ++j) o[4 + j] = (short)f2b(b[j]);
  *(bh8*)(dst + i) = o;
}

// f32 [segs*2^seg_shift, 1024] -> bf16 interleaved per 32 rows:
// src row rl of segment e -> dst row e*2^(seg_shift+1) + (rl>>5)*64 + (rl&31)
// + 32*half.  Used to build silu-fusable gate|up weight layouts.
__global__ __launch_bounds__(256) void f2b_convert_ilv(
    const float* __restrict__ src, u16* __restrict__ dst, int half,
    int seg_shift) {
  size_t i = ((size_t)blockIdx.x * 256 + threadIdx.x) * 8;
  int r = (int)(i >> 10), col = (int)(i & 1023);
  int rl = r & ((1 << seg_shift) - 1), e = r >> seg_shift;
  int dstrow = (e << (seg_shift + 1)) + ((rl >> 5) << 6) + (rl & 31) +
               (half << 5);
  fv4 a = *(const fv4*)(src + i);
  fv4 b = *(const fv4*)(src + i + 4);
  bh8 o;
#pragma unroll
  for (int j = 0; j < 4; ++j) o[j] = (short)f2b(a[j]);
#pragma unroll
  for (int j = 0; j < 4; ++j) o[4 + j] = (short)f2b(b[j]);
  *(bh8*)(dst + (size_t)dstrow * 1024 + col) = o;
}

// ---------------------------------------------------------------------------
extern "C" void kernel_launch(void* const* d_in, const int* in_sizes, int n_in,
                              void* d_out, int out_size, void* d_ws,
                              size_t ws_size, hipStream_t stream) {
  (void)in_sizes; (void)n_in; (void)out_size; (void)ws_size;
  const int Sc = 2048, Dc = 1024, NHc = 16, Tc = 4096, SH = 2048;

  const float* x   = (const float*)d_in[0];
  const float* fc  = (const float*)d_in[1];
  const float* fs  = (const float*)d_in[2];
  const float* wq  = (const float*)d_in[4];
  const float* wk  = (const float*)d_in[5];
  const float* wv  = (const float*)d_in[6];
  const float* wo  = (const float*)d_in[7];
  const float* anw = (const float*)d_in[8];
  const float* fnw = (const float*)d_in[9];
  const float* gw  = (const float*)d_in[10];
  const float* gb  = (const float*)d_in[11];
  const float* w1  = (const float*)d_in[12];
  const float* b1  = (const float*)d_in[13];
  const float* w2  = (const float*)d_in[14];
  const float* b2  = (const float*)d_in[15];
  const float* w3  = (const float*)d_in[16];
  const float* b3  = (const float*)d_in[17];
  const float* sgw = (const float*)d_in[18];
  const float* suw = (const float*)d_in[19];
  const float* sdw = (const float*)d_in[20];
  float* out = (float*)d_out;

  char* base = (char*)d_ws;
  size_t off = 0;
  auto alloc = [&](size_t bytes) -> void* {
    void* p = base + off;
    off += (bytes + 255) & ~(size_t)255;
    return p;
  };
  // weights: wqkv+wo FIRST (their region is reused as hf_b after wo-gemm)
  u16* wqkv_b = (u16*)alloc(2ull * 3072 * 1024);     // 6.29 MB
  u16* wo_b   = (u16*)alloc(2ull * 1024 * 1024);     // 2.10 MB
  u16* sgu_b  = (u16*)alloc(2ull * 4096 * 1024);     // 8.39 MB (interleaved)
  u16* sdw_b  = (u16*)alloc(2ull * 1024 * 2048);     // 4.19 MB
  u16* w13_b  = (u16*)alloc(2ull * 8 * 2048 * 1024); // 33.6 MB (interleaved)
  u16* w2_b   = (u16*)alloc(2ull * 8 * 1024 * 1024); // 16.8 MB
  // region A: qkv_out (25.2) -> eo (18.6)
  char* regA = (char*)alloc(2ull * Tc * 4096);
  // region B: h_b/qr/kr/vt/o_b (33.6) -> a13 (18.6)
  char* regB = (char*)alloc(2ull * (size_t)MAX_TILES * 128 * 2048);
  float* x2  = (float*)alloc(4ull * Tc * Dc);        // 16.8 MB
  u16* hs_b  = (u16*)alloc(2ull * Tc * SH);          // 16.8 MB
  int* topk_e = (int*)alloc(2ull * Tc * 4);
  float* topk_w = (float*)alloc(2ull * Tc * 4);
  int* pos_of = (int*)alloc(2ull * Tc * 4);
  int* rowid = (int*)alloc(2ull * Tc * 4);
  int* etok = (int*)alloc(8ull * 4096 * 4);
  int* meta = (int*)alloc(512 * 4);

  u16* qkv_out = (u16*)regA;
  u16* eo_c    = (u16*)regA;
  u16* h_b  = (u16*)regB;
  u16* qr   = (u16*)regB;
  u16* kr   = (u16*)(regB + 2ull * Tc * Dc);
  u16* vt_  = (u16*)(regB + 4ull * Tc * Dc);
  u16* o_b  = (u16*)(regB + 6ull * Tc * Dc);
  u16* a13_c = (u16*)regB;
  u16* hf_b = wqkv_b;  // overlays wqkv+wo after attention branch done

  auto conv = [&](const float* s, u16* d, size_t n) {
    f2b_convert<<<dim3((unsigned)(n / 2048)), 256, 0, stream>>>(s, d);
  };
  conv(wq, wqkv_b, (size_t)Dc * Dc);
  conv(wk, wqkv_b + 1048576, (size_t)Dc * Dc);
  conv(wv, wqkv_b + 2097152, (size_t)Dc * Dc);
  conv(wo, wo_b, (size_t)Dc * Dc);
  conv(sdw, sdw_b, (size_t)Dc * SH);
  conv(w2, w2_b, 8ull * 1024 * 1024);
  f2b_convert_ilv<<<1024, 256, 0, stream>>>(sgw, sgu_b, 0, 11);
  f2b_convert_ilv<<<1024, 256, 0, stream>>>(suw, sgu_b, 1, 11);
  f2b_convert_ilv<<<4096, 256, 0, stream>>>(w1, w13_b, 0, 10);
  f2b_convert_ilv<<<4096, 256, 0, stream>>>(w3, w13_b, 1, 10);

  // ---- attention branch ----
  rmsnorm_bf16<<<Tc, 256, 0, stream>>>(x, anw, h_b);
  gemm_bt<0, 128, 1><<<dim3(3072 / 128, Tc / 128), 256, 0, stream>>>(
      h_b, wqkv_b, Tc, 3072, Dc, qkv_out, nullptr, nullptr, nullptr, nullptr,
      nullptr, nullptr);
  rope_repack<<<dim3(Sc / 64, 2, 4), 256, 0, stream>>>(qkv_out, fc, fs, qr, kr,
                                                       vt_, Sc);
  attn_fwd<<<dim3(2 * NHc, Sc / 128), 256, 0, stream>>>(qr, kr, vt_, o_b, Sc,
                                                        NHc);
  gemm_bt<1, 64, 1><<<dim3(Dc / 128, Tc / 64), 256, 0, stream>>>(
      o_b, wo_b, Tc, Dc, Dc, nullptr, x2, x, nullptr, nullptr, nullptr,
      nullptr);

  // ---- ffn branch ----
  gate_topk<<<Tc / 4, 256, 0, stream>>>(x2, fnw, gw, gb, topk_e, topk_w,
                                        hf_b);
  route_tokens<<<1, 512, 0, stream>>>(topk_e, pos_of, etok, meta, rowid,
                                      2 * Tc);

  // merged: shared-expert gate|up (silu epilogue -> hs) + MoE w13 gather
  gemm_sgu_w13<<<dim3(1024 + 16 * MAX_TILES), 256, 0, stream>>>(
      hf_b, sgu_b, hs_b, w13_b, a13_c, b1, b3, meta, etok);

  // MoE w2 (TM=64 half-tiles)
  gemm_bt<6, 64><<<dim3(Dc / 128, 2 * MAX_TILES), 256, 0, stream>>>(
      a13_c, w2_b, /*lda=*/1024, Dc, 1024, eo_c, nullptr, nullptr, nullptr,
      b2, meta, etok);

  // final: out = x2 + hs @ sdw^T + w0*eo[r0] + w1*eo[r1]
  gemm_bt<9, 64, 1><<<dim3(Dc / 128, Tc / 64), 256, 0, stream>>>(
      hs_b, sdw_b, Tc, Dc, SH, eo_c, out, x2, nullptr, topk_w, rowid,
      nullptr);
}

// Round 12
// 384.389 us; speedup vs baseline: 1.0362x; 1.0362x over previous
//
#include <hip/hip_runtime.h>

// ---------------------------------------------------------------------------
// TransformerBlock on MI355X (gfx950), round 12:
//  - GEMMs: 512-thread / 8-wave blocks (wave grid 2x4, 64x32 out per wave).
//    Same LDS (64KB, 2 blocks/CU) but 16 waves/CU (4/SIMD) -- doubles the
//    TLP hiding the barrier+vmcnt stalls of the 2-phase K-loop.
//  - core unchanged: BK=64, dbuf, depth-1 counted vmcnt, raw barriers.
//  - attention (KVBLK=128), routing, fusions unchanged from round 11.
// ---------------------------------------------------------------------------

typedef unsigned short u16;
typedef __attribute__((ext_vector_type(8))) short bh8;   // 8 x bf16
typedef __attribute__((ext_vector_type(4))) float fv4;
typedef __attribute__((ext_vector_type(4))) unsigned uv4;
typedef __attribute__((ext_vector_type(2))) int iv2;

#define LOG2E 1.4426950408889634f
#define MAX_TILES 71

__device__ __forceinline__ float b2f(u16 u) {
  return __builtin_bit_cast(float, ((unsigned)u) << 16);
}
__device__ __forceinline__ u16 f2b(float f) {
  unsigned x = __builtin_bit_cast(unsigned, f);
  return (u16)((x + 0x7fffu + ((x >> 16) & 1u)) >> 16);  // RNE
}
__device__ __forceinline__ fv4 mfma16(bh8 a, bh8 b, fv4 c) {
  return __builtin_amdgcn_mfma_f32_16x16x32_bf16(a, b, c, 0, 0, 0);
}
__device__ __forceinline__ unsigned cvtpk(float lo, float hi) {
  unsigned r;
  asm("v_cvt_pk_bf16_f32 %0, %1, %2" : "=v"(r) : "v"(lo), "v"(hi));
  return r;
}

// Bijective XCD-chunk swizzle (m204).
__device__ __forceinline__ int xcd_swizzle1d(int flat, int nwg) {
  int q = nwg >> 3, r = nwg & 7;
  int xcd = flat & 7, idx = flat >> 3;
  return (xcd < r ? xcd * (q + 1) : r * (q + 1) + (xcd - r) * q) + idx;
}

#define GLD16(g, l)                                                        \
  __builtin_amdgcn_global_load_lds(                                        \
      (const __attribute__((address_space(1))) void*)(g),                  \
      (__attribute__((address_space(3))) void*)(l), 16, 0, 0)

// Read one MFMA fragment (16B) from a [rows][64] bf16 LDS tile whose rows are
// 128B and whose 16B blocks are XOR-swizzled by (row&7).
__device__ __forceinline__ bh8 lds_frag(const u16* base, int row, int b8) {
  int off = row * 128 + ((b8 * 16) ^ ((row & 7) << 4));
  return *(const bh8*)((const char*)base + off);
}

// ---------------------------------------------------------------------------
// Shared GEMM body (512 threads, 8 waves, wave grid 2x4):
// C[M,N] = A[M,K] (bf16) @ B[N,K]^T (bf16), f32 accumulate.
// TM: A-tile rows (128 or 64). B-tile is 128 cols. Per-wave out: (TM/2)x32.
// MODE 0: Cb = bf16(gemm)
// MODE 1: Cf = add1 + gemm
// MODE 6: compact-A grouped MoE (w2): lda via M; Cb = bf16(gemm + bias_e)
//         (TM=64: by encodes tile*2+half)
// MODE 7: interleaved silu (shared expert): Cb[.,N/2] = silu(g)*u
// MODE 8: gather-A grouped MoE w13, interleaved silu + biases
// MODE 9: final: Cf = add1 + gemm + w0*eo[r0] + w1*eo[r1]
// K-loop: BK=64, dbuf, depth-1 prefetch, counted vmcnt, raw barriers.
// ---------------------------------------------------------------------------
template <int MODE, int TM>
__device__ __forceinline__ void gemm_body(
    u16* AsB, u16* BsB, int bx, int by, const u16* __restrict__ A,
    const u16* __restrict__ B, int M, int N, int K, u16* __restrict__ Cb,
    float* __restrict__ Cf, const float* __restrict__ add1,
    const float* __restrict__ add2, const float* __restrict__ bias,
    const int* __restrict__ tmeta, const int* __restrict__ etok) {
  constexpr int MR = TM / 32;   // M-frags per wave: 128->4, 64->2
  constexpr int ACL = TM / 64;  // A-chunks per thread: 128->2, 64->1
  const int lane = threadIdx.x & 63;
  const int wid = threadIdx.x >> 6;       // 0..7
  const int wr = wid >> 2, wc = wid & 3;  // wave grid 2x4
  const int n0 = bx * 128;
  const int l15 = lane & 15;
  const int rr = lane >> 3;
  const int b8s = (lane & 7) ^ rr;
  const int ldA = (MODE == 6) ? M : K;

  int m0 = 0, e = 0, m0l = 0, cnt = 0, row0 = 0;
  const u16* Bp = B;
  if constexpr (MODE == 6 || MODE == 8) {
    int tile = by, half = 0;
    if constexpr (MODE == 6 && TM == 64) {
      tile = by >> 1;
      half = by & 1;
    }
    if (tile >= tmeta[0]) return;
    e = tmeta[16 + tile * 4];
    m0l = tmeta[17 + tile * 4];
    cnt = tmeta[18 + tile * 4];
    row0 = tmeta[19 + tile * 4] + half * 64;
    Bp = B + (size_t)e * N * K;
  } else {
    m0 = by * TM;
  }

  const u16* Arow[ACL];
  const u16* Brow[2];
#pragma unroll
  for (int i = 0; i < ACL; ++i) {
    int c = wid * ACL + i;
    int row = c * 8 + rr;
    if constexpr (MODE == 8) {
      int li = m0l + row;
      li = li < cnt ? li : cnt - 1;
      int tok = etok[e * 4096 + li];
      Arow[i] = A + (size_t)tok * ldA + b8s * 8;
    } else if constexpr (MODE == 6) {
      Arow[i] = A + (size_t)(row0 + row) * ldA + b8s * 8;
    } else {
      Arow[i] = A + (size_t)(m0 + row) * ldA + b8s * 8;
    }
  }
#pragma unroll
  for (int i = 0; i < 2; ++i)
    Brow[i] = Bp + (size_t)(n0 + (wid * 2 + i) * 8 + rr) * K + b8s * 8;

  fv4 acc[MR][2] = {};
  const int nt = K >> 6;

  // prologue: stage tile 0 into buffer 0
#pragma unroll
  for (int i = 0; i < ACL; ++i)
    GLD16(Arow[i], &AsB[(wid * ACL + i) * 512]);
#pragma unroll
  for (int i = 0; i < 2; ++i)
    GLD16(Brow[i], &BsB[(wid * 2 + i) * 512]);

  for (int t = 0; t < nt; ++t) {
    const int cur = t & 1;
    u16* Asc = AsB + cur * (TM * 64);
    u16* Bsc = BsB + cur * (128 * 64);
    if (t + 1 < nt) {
      const int k0 = (t + 1) * 64;
      u16* Asn = AsB + (cur ^ 1) * (TM * 64);
      u16* Bsn = BsB + (cur ^ 1) * (128 * 64);
#pragma unroll
      for (int i = 0; i < ACL; ++i)
        GLD16(Arow[i] + k0, &Asn[(wid * ACL + i) * 512]);
#pragma unroll
      for (int i = 0; i < 2; ++i)
        GLD16(Brow[i] + k0, &Bsn[(wid * 2 + i) * 512]);
      // wait only for the OLDEST (cur-tile) loads; next-tile stays in flight
      if constexpr (ACL == 2)
        asm volatile("s_waitcnt vmcnt(4)" ::: "memory");
      else
        asm volatile("s_waitcnt vmcnt(3)" ::: "memory");
    } else {
      asm volatile("s_waitcnt vmcnt(0)" ::: "memory");
    }
    __builtin_amdgcn_s_barrier();          // buf[cur] visible to all waves
    __builtin_amdgcn_sched_barrier(0);     // pin ds_reads below barrier

#pragma unroll
    for (int ks = 0; ks < 2; ++ks) {
      int b8 = ks * 4 + (lane >> 4);
      bh8 af[MR], bf[2];
#pragma unroll
      for (int mi = 0; mi < MR; ++mi)
        af[mi] = lds_frag(Asc, wr * (16 * MR) + mi * 16 + l15, b8);
      if constexpr (MODE == 7 || MODE == 8) {
        int col0 = (wc >> 1) * 64 + (wc & 1) * 16;
        bf[0] = lds_frag(Bsc, col0 + l15, b8);
        bf[1] = lds_frag(Bsc, col0 + 32 + l15, b8);
      } else {
#pragma unroll
        for (int ni = 0; ni < 2; ++ni)
          bf[ni] = lds_frag(Bsc, wc * 32 + ni * 16 + l15, b8);
      }
      __builtin_amdgcn_s_setprio(1);
#pragma unroll
      for (int mi = 0; mi < MR; ++mi)
#pragma unroll
        for (int ni = 0; ni < 2; ++ni)
          acc[mi][ni] = mfma16(af[mi], bf[ni], acc[mi][ni]);
      __builtin_amdgcn_s_setprio(0);
    }
    __builtin_amdgcn_sched_barrier(0);     // pin reads above barrier
    __builtin_amdgcn_s_barrier();          // all waves done reading buf[cur]
    __builtin_amdgcn_sched_barrier(0);     // pin next stage below barrier
  }

  const int rbase = (MODE == 6 || MODE == 8) ? row0 : m0;
  const int r0b = rbase + wr * (16 * MR) + (lane >> 4) * 4;

  if constexpr (MODE == 7 || MODE == 8) {
    const int OUTN = N >> 1;
    const int c = (n0 >> 1) + (wc >> 1) * 32 + (wc & 1) * 16 + l15;
    const float* bb1 = nullptr;
    const float* bb3 = nullptr;
    if constexpr (MODE == 8) {
      bb1 = add1 + (size_t)e * OUTN;
      bb3 = add2 + (size_t)e * OUTN;
    }
#pragma unroll
    for (int mi = 0; mi < MR; ++mi) {
#pragma unroll
      for (int r = 0; r < 4; ++r) {
        int row = r0b + mi * 16 + r;
        float xg = acc[mi][0][r];
        float yu = acc[mi][1][r];
        if constexpr (MODE == 8) {
          xg += bb1[c];
          yu += bb3[c];
        }
        float s = xg / (1.f + __expf(-xg));
        Cb[(size_t)row * OUTN + c] = f2b(s * yu);
      }
    }
  } else if constexpr (MODE == 9) {
    const int c0b = n0 + wc * 32 + l15;
#pragma unroll
    for (int mi = 0; mi < MR; ++mi) {
#pragma unroll
      for (int r = 0; r < 4; ++r) {
        int row = r0b + mi * 16 + r;
        int g0 = tmeta[2 * row], g1 = tmeta[2 * row + 1];
        float w0 = bias[2 * row], w1 = bias[2 * row + 1];
        const u16* e0p = Cb + (size_t)g0 * 1024;
        const u16* e1p = Cb + (size_t)g1 * 1024;
#pragma unroll
        for (int ni = 0; ni < 2; ++ni) {
          int c = c0b + ni * 16;
          size_t idx = (size_t)row * N + c;
          Cf[idx] = add1[idx] + acc[mi][ni][r] + w0 * b2f(e0p[c]) +
                    w1 * b2f(e1p[c]);
        }
      }
    }
  } else {
    const int c0b = n0 + wc * 32 + l15;
    const float* bb = nullptr;
    if constexpr (MODE == 6) bb = bias + (size_t)e * N;
#pragma unroll
    for (int mi = 0; mi < MR; ++mi) {
#pragma unroll
      for (int ni = 0; ni < 2; ++ni) {
        int c = c0b + ni * 16;
#pragma unroll
        for (int r = 0; r < 4; ++r) {
          int row = r0b + mi * 16 + r;
          size_t idx = (size_t)row * N + c;
          float v = acc[mi][ni][r];
          if constexpr (MODE == 0) Cb[idx] = f2b(v);
          else if constexpr (MODE == 1) Cf[idx] = add1[idx] + v;
          else Cb[idx] = f2b(v + bb[c]);
        }
      }
    }
  }
}

// STILE=1: decode the (XCD-chunked) flat index as 8by x 4bx supertiles.
template <int MODE, int TM = 128, int STILE = 0>
__global__ __launch_bounds__(512) void gemm_bt(
    const u16* __restrict__ A, const u16* __restrict__ B, int M, int N, int K,
    u16* __restrict__ Cb, float* __restrict__ Cf,
    const float* __restrict__ add1, const float* __restrict__ add2,
    const float* __restrict__ bias, const int* __restrict__ tmeta,
    const int* __restrict__ etok) {
  __shared__ u16 As[2][TM * 64];
  __shared__ u16 Bs[2][128 * 64];
  const int gx = gridDim.x;
  int flat = (int)blockIdx.y * gx + (int)blockIdx.x;
  flat = xcd_swizzle1d(flat, gx * (int)gridDim.y);
  int bx, by;
  if constexpr (STILE) {
    int SX = gx >> 2;
    int sidx = flat >> 5, within = flat & 31;
    int sy = sidx / SX, sx = sidx - sy * SX;
    by = sy * 8 + (within >> 2);
    bx = sx * 4 + (within & 3);
  } else {
    by = flat / gx;
    bx = flat - by * gx;
  }
  gemm_body<MODE, TM>(&As[0][0], &Bs[0][0], bx, by, A, B, M, N, K, Cb, Cf,
                      add1, add2, bias, tmeta, etok);
}

// Merged shared-expert (MODE 7, supertiled 32x32) + MoE w13 (MODE 8).
__global__ __launch_bounds__(512) void gemm_sgu_w13(
    const u16* __restrict__ hf, const u16* __restrict__ sgu_w,
    u16* __restrict__ hs, const u16* __restrict__ w13_w,
    u16* __restrict__ a13, const float* __restrict__ b1,
    const float* __restrict__ b3, const int* __restrict__ meta,
    const int* __restrict__ etok) {
  __shared__ u16 As[2][128 * 64];
  __shared__ u16 Bs[2][128 * 64];
  const int nwg = 1024 + 16 * MAX_TILES;
  int flat = xcd_swizzle1d((int)blockIdx.x, nwg);
  if (flat < 1024) {
    // supertile decode: gx=32 (SX=8), gy=32
    int sidx = flat >> 5, within = flat & 31;
    int sy = sidx >> 3, sx = sidx & 7;
    int by = sy * 8 + (within >> 2);
    int bx = sx * 4 + (within & 3);
    gemm_body<7, 128>(&As[0][0], &Bs[0][0], bx, by, hf, sgu_w, 4096, 4096,
                      1024, hs, nullptr, nullptr, nullptr, nullptr, nullptr,
                      nullptr);
  } else {
    int idx = flat - 1024;
    int by = idx >> 4, bx = idx & 15;
    gemm_body<8, 128>(&As[0][0], &Bs[0][0], bx, by, hf, w13_w, 4096, 2048,
                      1024, a13, nullptr, b1, b3, nullptr, meta, etok);
  }
}

// ---------------------------------------------------------------------------
// RMSNorm: f32 [T,1024] -> bf16 [T,1024], one block per token.
// ---------------------------------------------------------------------------
__global__ __launch_bounds__(256) void rmsnorm_bf16(
    const float* __restrict__ x, const float* __restrict__ w,
    u16* __restrict__ out) {
  int t = blockIdx.x;
  const float* xr = x + (size_t)t * 1024;
  fv4 v = *(const fv4*)(xr + threadIdx.x * 4);
  float ss = v[0] * v[0] + v[1] * v[1] + v[2] * v[2] + v[3] * v[3];
#pragma unroll
  for (int off = 1; off < 64; off <<= 1) ss += __shfl_xor(ss, off);
  __shared__ float red[4];
  int lane = threadIdx.x & 63, wid = threadIdx.x >> 6;
  if (lane == 0) red[wid] = ss;
  __syncthreads();
  float inv = rsqrtf((red[0] + red[1] + red[2] + red[3]) * (1.0f / 1024.f) + 1e-6f);
  u16* op = out + (size_t)t * 1024 + threadIdx.x * 4;
  const float* wp = w + threadIdx.x * 4;
#pragma unroll
  for (int i = 0; i < 4; ++i) op[i] = f2b(v[i] * inv * wp[i]);
}

// ---------------------------------------------------------------------------
// RoPE + repack from fused qkv [T,3072]:
//   q,k -> rotated [B,NH,S,64]; v -> vt [B,NH,64,S] (transposed AND column-
//   permuted per 64-block: physical group pg=4ks+g holds logical j
//   {16ks+4g+r, 16ks+32+4g+r}).  Grid: (S/64, B, NH/4).
// ---------------------------------------------------------------------------
__global__ __launch_bounds__(256) void rope_repack(
    const u16* __restrict__ qkv, const float* __restrict__ fc,
    const float* __restrict__ fs, u16* __restrict__ qr, u16* __restrict__ kr,
    u16* __restrict__ vt, int S) {
  __shared__ u16 tile[64][65];
  const int s0 = blockIdx.x * 64;
  const int b = blockIdx.y;
  const int h0 = blockIdx.z * 4;
#pragma unroll 4
  for (int it = 0; it < 32; ++it) {
    int idx = threadIdx.x + it * 256;
    int tl = idx >> 7, rem = idx & 127;
    int h = h0 + (rem >> 5), i = rem & 31;
    int s = s0 + tl;
    float c = fc[s * 32 + i], sn = fs[s * 32 + i];
    size_t src = ((size_t)(b * S + s)) * 3072 + h * 64 + 2 * i;
    size_t dst = ((size_t)((b * 16 + h) * S + s)) * 64 + 2 * i;
    float a0 = b2f(qkv[src]), a1 = b2f(qkv[src + 1]);
    qr[dst] = f2b(a0 * c - a1 * sn);
    qr[dst + 1] = f2b(a0 * sn + a1 * c);
    float b0 = b2f(qkv[src + 1024]), b1 = b2f(qkv[src + 1025]);
    kr[dst] = f2b(b0 * c - b1 * sn);
    kr[dst + 1] = f2b(b0 * sn + b1 * c);
  }
  for (int hh = 0; hh < 4; ++hh) {
    int h = h0 + hh;
    __syncthreads();
    for (int cc = threadIdx.x; cc < 512; cc += 256) {
      int tl = cc >> 3, d8 = cc & 7;
      bh8 val = *(const bh8*)(qkv + ((size_t)(b * S + s0 + tl)) * 3072 + 2048 +
                              h * 64 + d8 * 8);
#pragma unroll
      for (int j = 0; j < 8; ++j) tile[tl][d8 * 8 + j] = (u16)val[j];
    }
    __syncthreads();
    for (int cc = threadIdx.x; cc < 512; cc += 256) {
      int d = cc >> 3, pg = cc & 7;
      int sbase = 16 * (pg >> 2) + 4 * (pg & 3);
      bh8 o;
#pragma unroll
      for (int j = 0; j < 8; ++j)
        o[j] = (short)tile[sbase + (j & 3) + ((j >> 2) << 5)][d];
      *(bh8*)(vt + ((size_t)((b * 16 + h) * 64 + d)) * S + s0 + pg * 8) = o;
    }
  }
}

// ---------------------------------------------------------------------------
// Flash attention (causal), paired q-tiles, KVBLK=128 staging (two 64-wide
// subtiles per buffer -> one barrier per 128 kv), hoisted shared K/V frags,
// MFMA row-sum, fma-folded scale, defer-max.
// Grid: (B*NH, nq/2). 4 waves x 16 q-rows.
// ---------------------------------------------------------------------------
__global__ __launch_bounds__(256) void attn_fwd(
    const u16* __restrict__ qr, const u16* __restrict__ kr,
    const u16* __restrict__ vt, u16* __restrict__ ob, int S, int NHc) {
  __shared__ u16 Ks[2][2][64 * 64];
  __shared__ u16 Vs[2][2][64 * 64];   // V^T subtiles, column-permuted
  const int lane = threadIdx.x & 63;
  const int wid = threadIdx.x >> 6;
  const int g = lane >> 4;
  const int l15 = lane & 15;
  const int bh = blockIdx.x;
  const int ia = blockIdx.y;
  const int nq = S / 64;
  const int qa0 = ia * 64;                 // light q-tile
  const int qb0 = (nq - 1 - ia) * 64;      // heavy q-tile
  const int b = bh / NHc, h = bh % NHc;
  const u16* qbase = qr + (size_t)bh * S * 64;
  const u16* kb = kr + (size_t)bh * S * 64;
  const u16* vb = vt + (size_t)bh * 64 * S;
  const float SC = 0.015625f * LOG2E;  // both ref scales, log2 domain
  const int rr = lane >> 3;
  const int b8s = (lane & 7) ^ rr;

  bh8 ONES;
#pragma unroll
  for (int j = 0; j < 8; ++j) ONES[j] = (short)0x3f80;  // bf16 1.0

  bh8 qfA[2], qfB[2];
  {
    const u16* qp = qbase + (size_t)(qa0 + wid * 16 + l15) * 64 + g * 8;
    qfA[0] = *(const bh8*)qp;
    qfA[1] = *(const bh8*)(qp + 32);
    qp = qbase + (size_t)(qb0 + wid * 16 + l15) * 64 + g * 8;
    qfB[0] = *(const bh8*)qp;
    qfB[1] = *(const bh8*)(qp + 32);
  }
  fv4 oaccA[4] = {}, oaccB[4] = {};
  fv4 lA = {}, lB = {};                // row-sums, C-layout (row = 4g+r)
  float mA = -1e30f, mB = -1e30f;
  const int nktB = nq - ia;            // 64-wide kv tiles for heavy q-tile
  const int nrounds = (nktB + 1) >> 1; // 128-wide staging rounds

  auto stage = [&](int buf, int j0, int nsub) {
    for (int s = 0; s < nsub; ++s) {
#pragma unroll
      for (int i = 0; i < 2; ++i) {
        int c = wid * 2 + i;
        int row = c * 8 + rr;
        GLD16(kb + (size_t)(j0 + s * 64 + row) * 64 + b8s * 8,
              &Ks[buf][s][c * 512]);
        GLD16(vb + (size_t)row * S + j0 + s * 64 + b8s * 8,
              &Vs[buf][s][c * 512]);
      }
    }
  };
  stage(0, 0, nktB > 1 ? 2 : 1);

  auto process = [&](const bh8 (&kf)[2][4], const bh8 (&vf)[2][4], int j0,
                     int q0x, bh8* qf, fv4* oacc, float& mrow, fv4& lrowC) {
    const int q_my = q0x + wid * 16 + l15;
    fv4 st[4] = {};
    __builtin_amdgcn_s_setprio(1);
#pragma unroll
    for (int ks = 0; ks < 2; ++ks)
#pragma unroll
      for (int jt = 0; jt < 4; ++jt)
        st[jt] = mfma16(kf[ks][jt], qf[ks], st[jt]);
    __builtin_amdgcn_s_setprio(0);

    // mask + max on RAW scores (SC > 0 so max commutes with the scale)
    float sr[4][4];
    float mloc = -1e30f;
    const int jb = j0 + 4 * g;
    if (j0 + 63 > q0x + wid * 16) {   // diagonal tile
#pragma unroll
      for (int jt = 0; jt < 4; ++jt)
#pragma unroll
        for (int r = 0; r < 4; ++r) {
          int j = jb + jt * 16 + r;
          float s = (j <= q_my) ? st[jt][r] : -1e30f;
          sr[jt][r] = s;
          mloc = fmaxf(mloc, s);
        }
    } else {                          // interior: fully visible
#pragma unroll
      for (int jt = 0; jt < 4; ++jt)
#pragma unroll
        for (int r = 0; r < 4; ++r) {
          sr[jt][r] = st[jt][r];
          mloc = fmaxf(mloc, st[jt][r]);
        }
    }
    mloc = fmaxf(mloc, __shfl_xor(mloc, 16));
    mloc = fmaxf(mloc, __shfl_xor(mloc, 32));
    mloc *= SC;                        // scaled row max (log2 domain)
    bool defer = __all(mloc <= mrow + 8.f);   // T13
    if (!defer) {
      float mnew = fmaxf(mrow, mloc);
      float sfac = exp2f(mrow - mnew);
      mrow = mnew;
      float sfC[4];
#pragma unroll
      for (int r = 0; r < 4; ++r) sfC[r] = __shfl(sfac, g * 4 + r);
#pragma unroll
      for (int dt = 0; dt < 4; ++dt)
#pragma unroll
        for (int r = 0; r < 4; ++r) oacc[dt][r] *= sfC[r];
#pragma unroll
      for (int r = 0; r < 4; ++r) lrowC[r] *= sfC[r];
    }
    float p[4][4];
#pragma unroll
    for (int jt = 0; jt < 4; ++jt)
#pragma unroll
      for (int r = 0; r < 4; ++r)
        p[jt][r] = exp2f(fmaf(sr[jt][r], SC, -mrow));

    // PV + row-sum via MFMA (pa slot (g,i) <-> logical j matching permuted V)
    __builtin_amdgcn_s_setprio(1);
    fv4 racc = {};
#pragma unroll
    for (int ks = 0; ks < 2; ++ks) {
      uv4 w;
      w[0] = cvtpk(p[ks][0], p[ks][1]);
      w[1] = cvtpk(p[ks][2], p[ks][3]);
      w[2] = cvtpk(p[ks + 2][0], p[ks + 2][1]);
      w[3] = cvtpk(p[ks + 2][2], p[ks + 2][3]);
      bh8 pa = __builtin_bit_cast(bh8, w);
      racc = mfma16(pa, ONES, racc);
#pragma unroll
      for (int dt = 0; dt < 4; ++dt)
        oacc[dt] = mfma16(pa, vf[ks][dt], oacc[dt]);
    }
    __builtin_amdgcn_s_setprio(0);
#pragma unroll
    for (int r = 0; r < 4; ++r) lrowC[r] += racc[r];
  };

  for (int rd = 0; rd < nrounds; ++rd) {
    __syncthreads();  // drains staging for buf[rd&1]; joins all waves
    int rem = nktB - (rd + 1) * 2;
    if (rem > 0) stage((rd + 1) & 1, (rd + 1) * 128, rem > 1 ? 2 : 1);
#pragma unroll
    for (int s = 0; s < 2; ++s) {
      int kt = rd * 2 + s;
      if (kt >= nktB) break;
      const int j0 = kt * 64;
      const u16* Kc = Ks[rd & 1][s];
      const u16* Vc = Vs[rd & 1][s];
      bh8 kf[2][4], vf[2][4];
#pragma unroll
      for (int ks = 0; ks < 2; ++ks) {
        int b8 = ks * 4 + g;
#pragma unroll
        for (int jt = 0; jt < 4; ++jt)
          kf[ks][jt] = lds_frag(Kc, jt * 16 + l15, b8);
#pragma unroll
        for (int dt = 0; dt < 4; ++dt)
          vf[ks][dt] = lds_frag(Vc, dt * 16 + l15, b8);
      }
      process(kf, vf, j0, qb0, qfB, oaccB, mB, lB);
      if (kt <= ia) process(kf, vf, j0, qa0, qfA, oaccA, mA, lA);
    }
  }

  auto wout = [&](fv4* oacc, fv4 lrowC, int q0x) {
#pragma unroll
    for (int dt = 0; dt < 4; ++dt)
#pragma unroll
      for (int r = 0; r < 4; ++r) {
        int row = q0x + wid * 16 + g * 4 + r;
        int col = dt * 16 + l15;
        ob[((size_t)b * S + row) * 1024 + h * 64 + col] =
            f2b(oacc[dt][r] / lrowC[r]);
      }
  };
  wout(oaccA, lA, qa0);
  wout(oaccB, lB, qb0);
}

// ---------------------------------------------------------------------------
// Gate + fused ffn-rmsnorm: computes top-2 AND writes hf_b = bf16(rmsnorm).
// ---------------------------------------------------------------------------
__global__ __launch_bounds__(256) void gate_topk(
    const float* __restrict__ x2, const float* __restrict__ nw,
    const float* __restrict__ gw, const float* __restrict__ gb,
    int* __restrict__ topk_e, float* __restrict__ topk_w,
    u16* __restrict__ hf) {
  int t = blockIdx.x * 4 + (threadIdx.x >> 6);
  int lane = threadIdx.x & 63;
  const float* xr = x2 + (size_t)t * 1024;
  float hv[16];
  float ss = 0.f;
#pragma unroll
  for (int i = 0; i < 4; ++i) {
    fv4 v = *(const fv4*)(xr + lane * 16 + i * 4);
#pragma unroll
    for (int j = 0; j < 4; ++j) {
      hv[i * 4 + j] = v[j];
      ss += v[j] * v[j];
    }
  }
#pragma unroll
  for (int off = 1; off < 64; off <<= 1) ss += __shfl_xor(ss, off);
  float inv = rsqrtf(ss * (1.0f / 1024.f) + 1e-6f);
  const fv4* nwp = (const fv4*)(nw + lane * 16);
#pragma unroll
  for (int i = 0; i < 4; ++i) {
    fv4 wv = nwp[i];
#pragma unroll
    for (int j = 0; j < 4; ++j) hv[i * 4 + j] *= inv * wv[j];
  }
  {  // fused rmsnorm output
    bh8 o0, o1;
#pragma unroll
    for (int j = 0; j < 8; ++j) {
      o0[j] = (short)f2b(hv[j]);
      o1[j] = (short)f2b(hv[8 + j]);
    }
    u16* hp = hf + (size_t)t * 1024 + lane * 16;
    *(bh8*)hp = o0;
    *(bh8*)(hp + 8) = o1;
  }
  float logit[8];
#pragma unroll
  for (int e = 0; e < 8; ++e) {
    const fv4* wp = (const fv4*)(gw + (size_t)e * 1024 + lane * 16);
    float s = 0.f;
#pragma unroll
    for (int i = 0; i < 4; ++i) {
      fv4 wv = wp[i];
#pragma unroll
      for (int j = 0; j < 4; ++j) s += hv[i * 4 + j] * wv[j];
    }
    logit[e] = s;
  }
#pragma unroll
  for (int off = 1; off < 64; off <<= 1)
#pragma unroll
    for (int e = 0; e < 8; ++e) logit[e] += __shfl_xor(logit[e], off);
  if (lane == 0) {
#pragma unroll
    for (int e = 0; e < 8; ++e) logit[e] += gb[e];
    float mx = logit[0];
#pragma unroll
    for (int e = 1; e < 8; ++e) mx = fmaxf(mx, logit[e]);
    float pe[8], se = 0.f;
#pragma unroll
    for (int e = 0; e < 8; ++e) { pe[e] = __expf(logit[e] - mx); se += pe[e]; }
    float rs = 1.f / se;
#pragma unroll
    for (int e = 0; e < 8; ++e) pe[e] *= rs;
    int i0 = 0;
    float b0 = pe[0];
#pragma unroll
    for (int e = 1; e < 8; ++e)
      if (pe[e] > b0) { b0 = pe[e]; i0 = e; }
    int i1 = -1;
    float b1v = -1.f;
#pragma unroll
    for (int e = 0; e < 8; ++e)
      if (e != i0 && pe[e] > b1v) { b1v = pe[e]; i1 = e; }
    topk_e[2 * t] = i0;
    topk_e[2 * t + 1] = i1;
    topk_w[2 * t] = b0;
    topk_w[2 * t + 1] = b1v;
  }
}

// One block, 8 waves: wave e ballot-ranks its tokens (deterministic order),
// thread 0 builds the padded tile map, then all threads fill rowid[2T]
// (compact row index of each token's two expert outputs).
__global__ __launch_bounds__(512) void route_tokens(
    const int* __restrict__ topk_e, int* __restrict__ pos_of,
    int* __restrict__ etok, int* __restrict__ meta, int* __restrict__ rowid,
    int T2) {
  __shared__ int scnt[8], sbase[8];
  const int e = threadIdx.x >> 6;
  const int lane = threadIdx.x & 63;
  int base = 0;
  for (int i0 = 0; i0 < T2; i0 += 128) {
    iv2 te = *(const iv2*)(topk_e + i0 + lane * 2);
    unsigned long long m0 = __ballot(te[0] == e);
    unsigned long long m1 = __ballot(te[1] == e);
    unsigned long long lt = (1ull << lane) - 1;
    int pre = __popcll(m0 & lt) + __popcll(m1 & lt);
    if (te[0] == e) {
      int pos = base + pre;
      etok[e * 4096 + pos] = (i0 >> 1) + lane;
      pos_of[i0 + lane * 2] = pos;
      ++pre;
    }
    if (te[1] == e) {
      int pos = base + pre;
      etok[e * 4096 + pos] = (i0 >> 1) + lane;
      pos_of[i0 + lane * 2 + 1] = pos;
    }
    base += __popcll(m0) + __popcll(m1);
  }
  if (lane == 0) scnt[e] = base;
  __syncthreads();
  if (threadIdx.x == 0) {
    int tt = 0, rb = 0;
#pragma unroll
    for (int e2 = 0; e2 < 8; ++e2) {
      sbase[e2] = rb;
      int c = scnt[e2];
      int nt = (c + 127) >> 7;
      for (int i = 0; i < nt; ++i) {
        meta[16 + tt * 4] = e2;
        meta[17 + tt * 4] = i * 128;
        meta[18 + tt * 4] = c;
        meta[19 + tt * 4] = rb + i * 128;
        ++tt;
      }
      rb += nt * 128;
    }
    meta[0] = tt;
  }
  __syncthreads();
  for (int i = threadIdx.x; i < T2; i += 512)
    rowid[i] = sbase[topk_e[i]] + pos_of[i];
}

__global__ __launch_bounds__(256) void f2b_convert(
    const float* __restrict__ src, u16* __restrict__ dst) {
  size_t i = ((size_t)blockIdx.x * 256 + threadIdx.x) * 8;
  fv4 a = *(const fv4*)(src + i);
  fv4 b = *(const fv4*)(src + i + 4);
  bh8 o;
#pragma unroll
  for (int j = 0; j < 4; ++j) o[j] = (short)f2b(a[j]);
#pragma unroll
  for (int j = 0; j < 4; ++j) o[4 + j] = (short)f2b(b[j]);
  *(bh8*)(dst + i) = o;
}

// f32 [segs*2^seg_shift, 1024] -> bf16 interleaved per 32 rows:
// src row rl of segment e -> dst row e*2^(seg_shift+1) + (rl>>5)*64 + (rl&31)
// + 32*half.  Used to build silu-fusable gate|up weight layouts.
__global__ __launch_bounds__(256) void f2b_convert_ilv(
    const float* __restrict__ src, u16* __restrict__ dst, int half,
    int seg_shift) {
  size_t i = ((size_t)blockIdx.x * 256 + threadIdx.x) * 8;
  int r = (int)(i >> 10), col = (int)(i & 1023);
  int rl = r & ((1 << seg_shift) - 1), e = r >> seg_shift;
  int dstrow = (e << (seg_shift + 1)) + ((rl >> 5) << 6) + (rl & 31) +
               (half << 5);
  fv4 a = *(const fv4*)(src + i);
  fv4 b = *(const fv4*)(src + i + 4);
  bh8 o;
#pragma unroll
  for (int j = 0; j < 4; ++j) o[j] = (short)f2b(a[j]);
#pragma unroll
  for (int j = 0; j < 4; ++j) o[4 + j] = (short)f2b(b[j]);
  *(bh8*)(dst + (size_t)dstrow * 1024 + col) = o;
}

// ---------------------------------------------------------------------------
extern "C" void kernel_launch(void* const* d_in, const int* in_sizes, int n_in,
                              void* d_out, int out_size, void* d_ws,
                              size_t ws_size, hipStream_t stream) {
  (void)in_sizes; (void)n_in; (void)out_size; (void)ws_size;
  const int Sc = 2048, Dc = 1024, NHc = 16, Tc = 4096, SH = 2048;

  const float* x   = (const float*)d_in[0];
  const float* fc  = (const float*)d_in[1];
  const float* fs  = (const float*)d_in[2];
  const float* wq  = (const float*)d_in[4];
  const float* wk  = (const float*)d_in[5];
  const float* wv  = (const float*)d_in[6];
  const float* wo  = (const float*)d_in[7];
  const float* anw = (const float*)d_in[8];
  const float* fnw = (const float*)d_in[9];
  const float* gw  = (const float*)d_in[10];
  const float* gb  = (const float*)d_in[11];
  const float* w1  = (const float*)d_in[12];
  const float* b1  = (const float*)d_in[13];
  const float* w2  = (const float*)d_in[14];
  const float* b2  = (const float*)d_in[15];
  const float* w3  = (const float*)d_in[16];
  const float* b3  = (const float*)d_in[17];
  const float* sgw = (const float*)d_in[18];
  const float* suw = (const float*)d_in[19];
  const float* sdw = (const float*)d_in[20];
  float* out = (float*)d_out;

  char* base = (char*)d_ws;
  size_t off = 0;
  auto alloc = [&](size_t bytes) -> void* {
    void* p = base + off;
    off += (bytes + 255) & ~(size_t)255;
    return p;
  };
  // weights: wqkv+wo FIRST (their region is reused as hf_b after wo-gemm)
  u16* wqkv_b = (u16*)alloc(2ull * 3072 * 1024);     // 6.29 MB
  u16* wo_b   = (u16*)alloc(2ull * 1024 * 1024);     // 2.10 MB
  u16* sgu_b  = (u16*)alloc(2ull * 4096 * 1024);     // 8.39 MB (interleaved)
  u16* sdw_b  = (u16*)alloc(2ull * 1024 * 2048);     // 4.19 MB
  u16* w13_b  = (u16*)alloc(2ull * 8 * 2048 * 1024); // 33.6 MB (interleaved)
  u16* w2_b   = (u16*)alloc(2ull * 8 * 1024 * 1024); // 16.8 MB
  // region A: qkv_out (25.2) -> eo (18.6)
  char* regA = (char*)alloc(2ull * Tc * 4096);
  // region B: h_b/qr/kr/vt/o_b (33.6) -> a13 (18.6)
  char* regB = (char*)alloc(2ull * (size_t)MAX_TILES * 128 * 2048);
  float* x2  = (float*)alloc(4ull * Tc * Dc);        // 16.8 MB
  u16* hs_b  = (u16*)alloc(2ull * Tc * SH);          // 16.8 MB
  int* topk_e = (int*)alloc(2ull * Tc * 4);
  float* topk_w = (float*)alloc(2ull * Tc * 4);
  int* pos_of = (int*)alloc(2ull * Tc * 4);
  int* rowid = (int*)alloc(2ull * Tc * 4);
  int* etok = (int*)alloc(8ull * 4096 * 4);
  int* meta = (int*)alloc(512 * 4);

  u16* qkv_out = (u16*)regA;
  u16* eo_c    = (u16*)regA;
  u16* h_b  = (u16*)regB;
  u16* qr   = (u16*)regB;
  u16* kr   = (u16*)(regB + 2ull * Tc * Dc);
  u16* vt_  = (u16*)(regB + 4ull * Tc * Dc);
  u16* o_b  = (u16*)(regB + 6ull * Tc * Dc);
  u16* a13_c = (u16*)regB;
  u16* hf_b = wqkv_b;  // overlays wqkv+wo after attention branch done

  auto conv = [&](const float* s, u16* d, size_t n) {
    f2b_convert<<<dim3((unsigned)(n / 2048)), 256, 0, stream>>>(s, d);
  };
  conv(wq, wqkv_b, (size_t)Dc * Dc);
  conv(wk, wqkv_b + 1048576, (size_t)Dc * Dc);
  conv(wv, wqkv_b + 2097152, (size_t)Dc * Dc);
  conv(wo, wo_b, (size_t)Dc * Dc);
  conv(sdw, sdw_b, (size_t)Dc * SH);
  conv(w2, w2_b, 8ull * 1024 * 1024);
  f2b_convert_ilv<<<1024, 256, 0, stream>>>(sgw, sgu_b, 0, 11);
  f2b_convert_ilv<<<1024, 256, 0, stream>>>(suw, sgu_b, 1, 11);
  f2b_convert_ilv<<<4096, 256, 0, stream>>>(w1, w13_b, 0, 10);
  f2b_convert_ilv<<<4096, 256, 0, stream>>>(w3, w13_b, 1, 10);

  // ---- attention branch ----
  rmsnorm_bf16<<<Tc, 256, 0, stream>>>(x, anw, h_b);
  gemm_bt<0, 128, 1><<<dim3(3072 / 128, Tc / 128), 512, 0, stream>>>(
      h_b, wqkv_b, Tc, 3072, Dc, qkv_out, nullptr, nullptr, nullptr, nullptr,
      nullptr, nullptr);
  rope_repack<<<dim3(Sc / 64, 2, 4), 256, 0, stream>>>(qkv_out, fc, fs, qr, kr,
                                                       vt_, Sc);
  attn_fwd<<<dim3(2 * NHc, Sc / 128), 256, 0, stream>>>(qr, kr, vt_, o_b, Sc,
                                                        NHc);
  gemm_bt<1, 64, 1><<<dim3(Dc / 128, Tc / 64), 512, 0, stream>>>(
      o_b, wo_b, Tc, Dc, Dc, nullptr, x2, x, nullptr, nullptr, nullptr,
      nullptr);

  // ---- ffn branch ----
  gate_topk<<<Tc / 4, 256, 0, stream>>>(x2, fnw, gw, gb, topk_e, topk_w,
                                        hf_b);
  route_tokens<<<1, 512, 0, stream>>>(topk_e, pos_of, etok, meta, rowid,
                                      2 * Tc);

  // merged: shared-expert gate|up (silu epilogue -> hs) + MoE w13 gather
  gemm_sgu_w13<<<dim3(1024 + 16 * MAX_TILES), 512, 0, stream>>>(
      hf_b, sgu_b, hs_b, w13_b, a13_c, b1, b3, meta, etok);

  // MoE w2 (TM=64 half-tiles)
  gemm_bt<6, 64><<<dim3(Dc / 128, 2 * MAX_TILES), 512, 0, stream>>>(
      a13_c, w2_b, /*lda=*/1024, Dc, 1024, eo_c, nullptr, nullptr, nullptr,
      b2, meta, etok);

  // final: out = x2 + hs @ sdw^T + w0*eo[r0] + w1*eo[r1]
  gemm_bt<9, 64, 1><<<dim3(Dc / 128, Tc / 64), 512, 0, stream>>>(
      hs_b, sdw_b, Tc, Dc, SH, eo_c, out, x2, nullptr, topk_w, rowid,
      nullptr);
}

// Round 13
// 363.276 us; speedup vs baseline: 1.0964x; 1.0581x over previous
//
#include <hip/hip_runtime.h>

// ---------------------------------------------------------------------------
// TransformerBlock on MI355X (gfx950), round 13:
//  - mega_prep: ALL weight conversions (plain + interleaved) and the first
//    rmsnorm merged into ONE dispatch (was 11) -- kills launch gaps and
//    GPU-underfilling convert tails.
//  - GEMMs: 512-thread / 8-wave blocks, BK=64, dbuf, depth-1 counted vmcnt,
//    raw barriers, XCD-chunk + 2D supertile ordering (round-12 proven).
//  - attention (paired q-tiles, KVBLK=128), atomic-free routing, fused
//    epilogues unchanged.
// ---------------------------------------------------------------------------

typedef unsigned short u16;
typedef __attribute__((ext_vector_type(8))) short bh8;   // 8 x bf16
typedef __attribute__((ext_vector_type(4))) float fv4;
typedef __attribute__((ext_vector_type(4))) unsigned uv4;
typedef __attribute__((ext_vector_type(2))) int iv2;

#define LOG2E 1.4426950408889634f
#define MAX_TILES 71

__device__ __forceinline__ float b2f(u16 u) {
  return __builtin_bit_cast(float, ((unsigned)u) << 16);
}
__device__ __forceinline__ u16 f2b(float f) {
  unsigned x = __builtin_bit_cast(unsigned, f);
  return (u16)((x + 0x7fffu + ((x >> 16) & 1u)) >> 16);  // RNE
}
__device__ __forceinline__ fv4 mfma16(bh8 a, bh8 b, fv4 c) {
  return __builtin_amdgcn_mfma_f32_16x16x32_bf16(a, b, c, 0, 0, 0);
}
__device__ __forceinline__ unsigned cvtpk(float lo, float hi) {
  unsigned r;
  asm("v_cvt_pk_bf16_f32 %0, %1, %2" : "=v"(r) : "v"(lo), "v"(hi));
  return r;
}

// Bijective XCD-chunk swizzle (m204).
__device__ __forceinline__ int xcd_swizzle1d(int flat, int nwg) {
  int q = nwg >> 3, r = nwg & 7;
  int xcd = flat & 7, idx = flat >> 3;
  return (xcd < r ? xcd * (q + 1) : r * (q + 1) + (xcd - r) * q) + idx;
}

#define GLD16(g, l)                                                        \
  __builtin_amdgcn_global_load_lds(                                        \
      (const __attribute__((address_space(1))) void*)(g),                  \
      (__attribute__((address_space(3))) void*)(l), 16, 0, 0)

// Read one MFMA fragment (16B) from a [rows][64] bf16 LDS tile whose rows are
// 128B and whose 16B blocks are XOR-swizzled by (row&7).
__device__ __forceinline__ bh8 lds_frag(const u16* base, int row, int b8) {
  int off = row * 128 + ((b8 * 16) ^ ((row & 7) << 4));
  return *(const bh8*)((const char*)base + off);
}

// ---------------------------------------------------------------------------
// Shared GEMM body (512 threads, 8 waves, wave grid 2x4):
// C[M,N] = A[M,K] (bf16) @ B[N,K]^T (bf16), f32 accumulate.
// TM: A-tile rows (128 or 64). B-tile is 128 cols. Per-wave out: (TM/2)x32.
// MODE 0: Cb = bf16(gemm)
// MODE 1: Cf = add1 + gemm
// MODE 6: compact-A grouped MoE (w2): lda via M; Cb = bf16(gemm + bias_e)
//         (TM=64: by encodes tile*2+half)
// MODE 7: interleaved silu (shared expert): Cb[.,N/2] = silu(g)*u
// MODE 8: gather-A grouped MoE w13, interleaved silu + biases
// MODE 9: final: Cf = add1 + gemm + w0*eo[r0] + w1*eo[r1]
// K-loop: BK=64, dbuf, depth-1 prefetch, counted vmcnt, raw barriers.
// ---------------------------------------------------------------------------
template <int MODE, int TM>
__device__ __forceinline__ void gemm_body(
    u16* AsB, u16* BsB, int bx, int by, const u16* __restrict__ A,
    const u16* __restrict__ B, int M, int N, int K, u16* __restrict__ Cb,
    float* __restrict__ Cf, const float* __restrict__ add1,
    const float* __restrict__ add2, const float* __restrict__ bias,
    const int* __restrict__ tmeta, const int* __restrict__ etok) {
  constexpr int MR = TM / 32;   // M-frags per wave: 128->4, 64->2
  constexpr int ACL = TM / 64;  // A-chunks per thread: 128->2, 64->1
  const int lane = threadIdx.x & 63;
  const int wid = threadIdx.x >> 6;       // 0..7
  const int wr = wid >> 2, wc = wid & 3;  // wave grid 2x4
  const int n0 = bx * 128;
  const int l15 = lane & 15;
  const int rr = lane >> 3;
  const int b8s = (lane & 7) ^ rr;
  const int ldA = (MODE == 6) ? M : K;

  int m0 = 0, e = 0, m0l = 0, cnt = 0, row0 = 0;
  const u16* Bp = B;
  if constexpr (MODE == 6 || MODE == 8) {
    int tile = by, half = 0;
    if constexpr (MODE == 6 && TM == 64) {
      tile = by >> 1;
      half = by & 1;
    }
    if (tile >= tmeta[0]) return;
    e = tmeta[16 + tile * 4];
    m0l = tmeta[17 + tile * 4];
    cnt = tmeta[18 + tile * 4];
    row0 = tmeta[19 + tile * 4] + half * 64;
    Bp = B + (size_t)e * N * K;
  } else {
    m0 = by * TM;
  }

  const u16* Arow[ACL];
  const u16* Brow[2];
#pragma unroll
  for (int i = 0; i < ACL; ++i) {
    int c = wid * ACL + i;
    int row = c * 8 + rr;
    if constexpr (MODE == 8) {
      int li = m0l + row;
      li = li < cnt ? li : cnt - 1;
      int tok = etok[e * 4096 + li];
      Arow[i] = A + (size_t)tok * ldA + b8s * 8;
    } else if constexpr (MODE == 6) {
      Arow[i] = A + (size_t)(row0 + row) * ldA + b8s * 8;
    } else {
      Arow[i] = A + (size_t)(m0 + row) * ldA + b8s * 8;
    }
  }
#pragma unroll
  for (int i = 0; i < 2; ++i)
    Brow[i] = Bp + (size_t)(n0 + (wid * 2 + i) * 8 + rr) * K + b8s * 8;

  fv4 acc[MR][2] = {};
  const int nt = K >> 6;

  // prologue: stage tile 0 into buffer 0
#pragma unroll
  for (int i = 0; i < ACL; ++i)
    GLD16(Arow[i], &AsB[(wid * ACL + i) * 512]);
#pragma unroll
  for (int i = 0; i < 2; ++i)
    GLD16(Brow[i], &BsB[(wid * 2 + i) * 512]);

  for (int t = 0; t < nt; ++t) {
    const int cur = t & 1;
    u16* Asc = AsB + cur * (TM * 64);
    u16* Bsc = BsB + cur * (128 * 64);
    if (t + 1 < nt) {
      const int k0 = (t + 1) * 64;
      u16* Asn = AsB + (cur ^ 1) * (TM * 64);
      u16* Bsn = BsB + (cur ^ 1) * (128 * 64);
#pragma unroll
      for (int i = 0; i < ACL; ++i)
        GLD16(Arow[i] + k0, &Asn[(wid * ACL + i) * 512]);
#pragma unroll
      for (int i = 0; i < 2; ++i)
        GLD16(Brow[i] + k0, &Bsn[(wid * 2 + i) * 512]);
      // wait only for the OLDEST (cur-tile) loads; next-tile stays in flight
      if constexpr (ACL == 2)
        asm volatile("s_waitcnt vmcnt(4)" ::: "memory");
      else
        asm volatile("s_waitcnt vmcnt(3)" ::: "memory");
    } else {
      asm volatile("s_waitcnt vmcnt(0)" ::: "memory");
    }
    __builtin_amdgcn_s_barrier();          // buf[cur] visible to all waves
    __builtin_amdgcn_sched_barrier(0);     // pin ds_reads below barrier

#pragma unroll
    for (int ks = 0; ks < 2; ++ks) {
      int b8 = ks * 4 + (lane >> 4);
      bh8 af[MR], bf[2];
#pragma unroll
      for (int mi = 0; mi < MR; ++mi)
        af[mi] = lds_frag(Asc, wr * (16 * MR) + mi * 16 + l15, b8);
      if constexpr (MODE == 7 || MODE == 8) {
        int col0 = (wc >> 1) * 64 + (wc & 1) * 16;
        bf[0] = lds_frag(Bsc, col0 + l15, b8);
        bf[1] = lds_frag(Bsc, col0 + 32 + l15, b8);
      } else {
#pragma unroll
        for (int ni = 0; ni < 2; ++ni)
          bf[ni] = lds_frag(Bsc, wc * 32 + ni * 16 + l15, b8);
      }
      __builtin_amdgcn_s_setprio(1);
#pragma unroll
      for (int mi = 0; mi < MR; ++mi)
#pragma unroll
        for (int ni = 0; ni < 2; ++ni)
          acc[mi][ni] = mfma16(af[mi], bf[ni], acc[mi][ni]);
      __builtin_amdgcn_s_setprio(0);
    }
    __builtin_amdgcn_sched_barrier(0);     // pin reads above barrier
    __builtin_amdgcn_s_barrier();          // all waves done reading buf[cur]
    __builtin_amdgcn_sched_barrier(0);     // pin next stage below barrier
  }

  const int rbase = (MODE == 6 || MODE == 8) ? row0 : m0;
  const int r0b = rbase + wr * (16 * MR) + (lane >> 4) * 4;

  if constexpr (MODE == 7 || MODE == 8) {
    const int OUTN = N >> 1;
    const int c = (n0 >> 1) + (wc >> 1) * 32 + (wc & 1) * 16 + l15;
    const float* bb1 = nullptr;
    const float* bb3 = nullptr;
    if constexpr (MODE == 8) {
      bb1 = add1 + (size_t)e * OUTN;
      bb3 = add2 + (size_t)e * OUTN;
    }
#pragma unroll
    for (int mi = 0; mi < MR; ++mi) {
#pragma unroll
      for (int r = 0; r < 4; ++r) {
        int row = r0b + mi * 16 + r;
        float xg = acc[mi][0][r];
        float yu = acc[mi][1][r];
        if constexpr (MODE == 8) {
          xg += bb1[c];
          yu += bb3[c];
        }
        float s = xg / (1.f + __expf(-xg));
        Cb[(size_t)row * OUTN + c] = f2b(s * yu);
      }
    }
  } else if constexpr (MODE == 9) {
    const int c0b = n0 + wc * 32 + l15;
#pragma unroll
    for (int mi = 0; mi < MR; ++mi) {
#pragma unroll
      for (int r = 0; r < 4; ++r) {
        int row = r0b + mi * 16 + r;
        int g0 = tmeta[2 * row], g1 = tmeta[2 * row + 1];
        float w0 = bias[2 * row], w1 = bias[2 * row + 1];
        const u16* e0p = Cb + (size_t)g0 * 1024;
        const u16* e1p = Cb + (size_t)g1 * 1024;
#pragma unroll
        for (int ni = 0; ni < 2; ++ni) {
          int c = c0b + ni * 16;
          size_t idx = (size_t)row * N + c;
          Cf[idx] = add1[idx] + acc[mi][ni][r] + w0 * b2f(e0p[c]) +
                    w1 * b2f(e1p[c]);
        }
      }
    }
  } else {
    const int c0b = n0 + wc * 32 + l15;
    const float* bb = nullptr;
    if constexpr (MODE == 6) bb = bias + (size_t)e * N;
#pragma unroll
    for (int mi = 0; mi < MR; ++mi) {
#pragma unroll
      for (int ni = 0; ni < 2; ++ni) {
        int c = c0b + ni * 16;
#pragma unroll
        for (int r = 0; r < 4; ++r) {
          int row = r0b + mi * 16 + r;
          size_t idx = (size_t)row * N + c;
          float v = acc[mi][ni][r];
          if constexpr (MODE == 0) Cb[idx] = f2b(v);
          else if constexpr (MODE == 1) Cf[idx] = add1[idx] + v;
          else Cb[idx] = f2b(v + bb[c]);
        }
      }
    }
  }
}

// STILE=1: decode the (XCD-chunked) flat index as 8by x 4bx supertiles.
template <int MODE, int TM = 128, int STILE = 0>
__global__ __launch_bounds__(512) void gemm_bt(
    const u16* __restrict__ A, const u16* __restrict__ B, int M, int N, int K,
    u16* __restrict__ Cb, float* __restrict__ Cf,
    const float* __restrict__ add1, const float* __restrict__ add2,
    const float* __restrict__ bias, const int* __restrict__ tmeta,
    const int* __restrict__ etok) {
  __shared__ u16 As[2][TM * 64];
  __shared__ u16 Bs[2][128 * 64];
  const int gx = gridDim.x;
  int flat = (int)blockIdx.y * gx + (int)blockIdx.x;
  flat = xcd_swizzle1d(flat, gx * (int)gridDim.y);
  int bx, by;
  if constexpr (STILE) {
    int SX = gx >> 2;
    int sidx = flat >> 5, within = flat & 31;
    int sy = sidx / SX, sx = sidx - sy * SX;
    by = sy * 8 + (within >> 2);
    bx = sx * 4 + (within & 3);
  } else {
    by = flat / gx;
    bx = flat - by * gx;
  }
  gemm_body<MODE, TM>(&As[0][0], &Bs[0][0], bx, by, A, B, M, N, K, Cb, Cf,
                      add1, add2, bias, tmeta, etok);
}

// Merged shared-expert (MODE 7, supertiled 32x32) + MoE w13 (MODE 8).
__global__ __launch_bounds__(512) void gemm_sgu_w13(
    const u16* __restrict__ hf, const u16* __restrict__ sgu_w,
    u16* __restrict__ hs, const u16* __restrict__ w13_w,
    u16* __restrict__ a13, const float* __restrict__ b1,
    const float* __restrict__ b3, const int* __restrict__ meta,
    const int* __restrict__ etok) {
  __shared__ u16 As[2][128 * 64];
  __shared__ u16 Bs[2][128 * 64];
  const int nwg = 1024 + 16 * MAX_TILES;
  int flat = xcd_swizzle1d((int)blockIdx.x, nwg);
  if (flat < 1024) {
    // supertile decode: gx=32 (SX=8), gy=32
    int sidx = flat >> 5, within = flat & 31;
    int sy = sidx >> 3, sx = sidx & 7;
    int by = sy * 8 + (within >> 2);
    int bx = sx * 4 + (within & 3);
    gemm_body<7, 128>(&As[0][0], &Bs[0][0], bx, by, hf, sgu_w, 4096, 4096,
                      1024, hs, nullptr, nullptr, nullptr, nullptr, nullptr,
                      nullptr);
  } else {
    int idx = flat - 1024;
    int by = idx >> 4, bx = idx & 15;
    gemm_body<8, 128>(&As[0][0], &Bs[0][0], bx, by, hf, w13_w, 4096, 2048,
                      1024, a13, nullptr, b1, b3, nullptr, meta, etok);
  }
}

// ---------------------------------------------------------------------------
// mega_prep: ALL weight conversions + first rmsnorm in ONE dispatch.
// Block map (256 threads each):
//   [0,512)      wq  -> wqkv_b
//   [512,1024)   wk  -> wqkv_b+1M
//   [1024,1536)  wv  -> wqkv_b+2M
//   [1536,2048)  wo  -> wo_b
//   [2048,3072)  sdw -> sdw_b
//   [3072,7168)  w2  -> w2_b
//   [7168,8192)  sgw -> sgu_b  (ilv half=0 shift=11)
//   [8192,9216)  suw -> sgu_b  (ilv half=1 shift=11)
//   [9216,13312) w1  -> w13_b  (ilv half=0 shift=10)
//   [13312,17408) w3 -> w13_b  (ilv half=1 shift=10)
//   [17408,21504) rmsnorm(x, anw) -> h_b  (one block per token)
// ---------------------------------------------------------------------------
__device__ __forceinline__ void conv_plain(const float* src, u16* dst,
                                           int lb) {
  size_t i = ((size_t)lb * 256 + threadIdx.x) * 8;
  fv4 a = *(const fv4*)(src + i);
  fv4 b = *(const fv4*)(src + i + 4);
  bh8 o;
#pragma unroll
  for (int j = 0; j < 4; ++j) o[j] = (short)f2b(a[j]);
#pragma unroll
  for (int j = 0; j < 4; ++j) o[4 + j] = (short)f2b(b[j]);
  *(bh8*)(dst + i) = o;
}
__device__ __forceinline__ void conv_ilv(const float* src, u16* dst, int lb,
                                         int half, int seg_shift) {
  size_t i = ((size_t)lb * 256 + threadIdx.x) * 8;
  int r = (int)(i >> 10), col = (int)(i & 1023);
  int rl = r & ((1 << seg_shift) - 1), e = r >> seg_shift;
  int dstrow = (e << (seg_shift + 1)) + ((rl >> 5) << 6) + (rl & 31) +
               (half << 5);
  fv4 a = *(const fv4*)(src + i);
  fv4 b = *(const fv4*)(src + i + 4);
  bh8 o;
#pragma unroll
  for (int j = 0; j < 4; ++j) o[j] = (short)f2b(a[j]);
#pragma unroll
  for (int j = 0; j < 4; ++j) o[4 + j] = (short)f2b(b[j]);
  *(bh8*)(dst + (size_t)dstrow * 1024 + col) = o;
}

__global__ __launch_bounds__(256) void mega_prep(
    const float* __restrict__ wq, const float* __restrict__ wk,
    const float* __restrict__ wv, const float* __restrict__ wo,
    const float* __restrict__ sdw, const float* __restrict__ w2,
    const float* __restrict__ sgw, const float* __restrict__ suw,
    const float* __restrict__ w1, const float* __restrict__ w3,
    const float* __restrict__ x, const float* __restrict__ anw,
    u16* __restrict__ wqkv_b, u16* __restrict__ wo_b,
    u16* __restrict__ sdw_b, u16* __restrict__ w2_b,
    u16* __restrict__ sgu_b, u16* __restrict__ w13_b,
    u16* __restrict__ h_b) {
  __shared__ float red[4];
  const int bid = blockIdx.x;
  if (bid < 512) {
    conv_plain(wq, wqkv_b, bid);
  } else if (bid < 1024) {
    conv_plain(wk, wqkv_b + 1048576, bid - 512);
  } else if (bid < 1536) {
    conv_plain(wv, wqkv_b + 2097152, bid - 1024);
  } else if (bid < 2048) {
    conv_plain(wo, wo_b, bid - 1536);
  } else if (bid < 3072) {
    conv_plain(sdw, sdw_b, bid - 2048);
  } else if (bid < 7168) {
    conv_plain(w2, w2_b, bid - 3072);
  } else if (bid < 8192) {
    conv_ilv(sgw, sgu_b, bid - 7168, 0, 11);
  } else if (bid < 9216) {
    conv_ilv(suw, sgu_b, bid - 8192, 1, 11);
  } else if (bid < 13312) {
    conv_ilv(w1, w13_b, bid - 9216, 0, 10);
  } else if (bid < 17408) {
    conv_ilv(w3, w13_b, bid - 13312, 1, 10);
  } else {
    int t = bid - 17408;
    const float* xr = x + (size_t)t * 1024;
    fv4 v = *(const fv4*)(xr + threadIdx.x * 4);
    float ss = v[0] * v[0] + v[1] * v[1] + v[2] * v[2] + v[3] * v[3];
#pragma unroll
    for (int off = 1; off < 64; off <<= 1) ss += __shfl_xor(ss, off);
    int lane = threadIdx.x & 63, wid = threadIdx.x >> 6;
    if (lane == 0) red[wid] = ss;
    __syncthreads();
    float inv =
        rsqrtf((red[0] + red[1] + red[2] + red[3]) * (1.0f / 1024.f) + 1e-6f);
    u16* op = h_b + (size_t)t * 1024 + threadIdx.x * 4;
    const float* wp = anw + threadIdx.x * 4;
#pragma unroll
    for (int i = 0; i < 4; ++i) op[i] = f2b(v[i] * inv * wp[i]);
  }
}

// ---------------------------------------------------------------------------
// RoPE + repack from fused qkv [T,3072]:
//   q,k -> rotated [B,NH,S,64]; v -> vt [B,NH,64,S] (transposed AND column-
//   permuted per 64-block: physical group pg=4ks+g holds logical j
//   {16ks+4g+r, 16ks+32+4g+r}).  Grid: (S/64, B, NH/4).
// ---------------------------------------------------------------------------
__global__ __launch_bounds__(256) void rope_repack(
    const u16* __restrict__ qkv, const float* __restrict__ fc,
    const float* __restrict__ fs, u16* __restrict__ qr, u16* __restrict__ kr,
    u16* __restrict__ vt, int S) {
  __shared__ u16 tile[64][65];
  const int s0 = blockIdx.x * 64;
  const int b = blockIdx.y;
  const int h0 = blockIdx.z * 4;
#pragma unroll 4
  for (int it = 0; it < 32; ++it) {
    int idx = threadIdx.x + it * 256;
    int tl = idx >> 7, rem = idx & 127;
    int h = h0 + (rem >> 5), i = rem & 31;
    int s = s0 + tl;
    float c = fc[s * 32 + i], sn = fs[s * 32 + i];
    size_t src = ((size_t)(b * S + s)) * 3072 + h * 64 + 2 * i;
    size_t dst = ((size_t)((b * 16 + h) * S + s)) * 64 + 2 * i;
    float a0 = b2f(qkv[src]), a1 = b2f(qkv[src + 1]);
    qr[dst] = f2b(a0 * c - a1 * sn);
    qr[dst + 1] = f2b(a0 * sn + a1 * c);
    float b0 = b2f(qkv[src + 1024]), b1 = b2f(qkv[src + 1025]);
    kr[dst] = f2b(b0 * c - b1 * sn);
    kr[dst + 1] = f2b(b0 * sn + b1 * c);
  }
  for (int hh = 0; hh < 4; ++hh) {
    int h = h0 + hh;
    __syncthreads();
    for (int cc = threadIdx.x; cc < 512; cc += 256) {
      int tl = cc >> 3, d8 = cc & 7;
      bh8 val = *(const bh8*)(qkv + ((size_t)(b * S + s0 + tl)) * 3072 + 2048 +
                              h * 64 + d8 * 8);
#pragma unroll
      for (int j = 0; j < 8; ++j) tile[tl][d8 * 8 + j] = (u16)val[j];
    }
    __syncthreads();
    for (int cc = threadIdx.x; cc < 512; cc += 256) {
      int d = cc >> 3, pg = cc & 7;
      int sbase = 16 * (pg >> 2) + 4 * (pg & 3);
      bh8 o;
#pragma unroll
      for (int j = 0; j < 8; ++j)
        o[j] = (short)tile[sbase + (j & 3) + ((j >> 2) << 5)][d];
      *(bh8*)(vt + ((size_t)((b * 16 + h) * 64 + d)) * S + s0 + pg * 8) = o;
    }
  }
}

// ---------------------------------------------------------------------------
// Flash attention (causal), paired q-tiles, KVBLK=128 staging (two 64-wide
// subtiles per buffer -> one barrier per 128 kv), hoisted shared K/V frags,
// MFMA row-sum, fma-folded scale, defer-max.
// Grid: (B*NH, nq/2). 4 waves x 16 q-rows.
// ---------------------------------------------------------------------------
__global__ __launch_bounds__(256) void attn_fwd(
    const u16* __restrict__ qr, const u16* __restrict__ kr,
    const u16* __restrict__ vt, u16* __restrict__ ob, int S, int NHc) {
  __shared__ u16 Ks[2][2][64 * 64];
  __shared__ u16 Vs[2][2][64 * 64];   // V^T subtiles, column-permuted
  const int lane = threadIdx.x & 63;
  const int wid = threadIdx.x >> 6;
  const int g = lane >> 4;
  const int l15 = lane & 15;
  const int bh = blockIdx.x;
  const int ia = blockIdx.y;
  const int nq = S / 64;
  const int qa0 = ia * 64;                 // light q-tile
  const int qb0 = (nq - 1 - ia) * 64;      // heavy q-tile
  const int b = bh / NHc, h = bh % NHc;
  const u16* qbase = qr + (size_t)bh * S * 64;
  const u16* kb = kr + (size_t)bh * S * 64;
  const u16* vb = vt + (size_t)bh * 64 * S;
  const float SC = 0.015625f * LOG2E;  // both ref scales, log2 domain
  const int rr = lane >> 3;
  const int b8s = (lane & 7) ^ rr;

  bh8 ONES;
#pragma unroll
  for (int j = 0; j < 8; ++j) ONES[j] = (short)0x3f80;  // bf16 1.0

  bh8 qfA[2], qfB[2];
  {
    const u16* qp = qbase + (size_t)(qa0 + wid * 16 + l15) * 64 + g * 8;
    qfA[0] = *(const bh8*)qp;
    qfA[1] = *(const bh8*)(qp + 32);
    qp = qbase + (size_t)(qb0 + wid * 16 + l15) * 64 + g * 8;
    qfB[0] = *(const bh8*)qp;
    qfB[1] = *(const bh8*)(qp + 32);
  }
  fv4 oaccA[4] = {}, oaccB[4] = {};
  fv4 lA = {}, lB = {};                // row-sums, C-layout (row = 4g+r)
  float mA = -1e30f, mB = -1e30f;
  const int nktB = nq - ia;            // 64-wide kv tiles for heavy q-tile
  const int nrounds = (nktB + 1) >> 1; // 128-wide staging rounds

  auto stage = [&](int buf, int j0, int nsub) {
    for (int s = 0; s < nsub; ++s) {
#pragma unroll
      for (int i = 0; i < 2; ++i) {
        int c = wid * 2 + i;
        int row = c * 8 + rr;
        GLD16(kb + (size_t)(j0 + s * 64 + row) * 64 + b8s * 8,
              &Ks[buf][s][c * 512]);
        GLD16(vb + (size_t)row * S + j0 + s * 64 + b8s * 8,
              &Vs[buf][s][c * 512]);
      }
    }
  };
  stage(0, 0, nktB > 1 ? 2 : 1);

  auto process = [&](const bh8 (&kf)[2][4], const bh8 (&vf)[2][4], int j0,
                     int q0x, bh8* qf, fv4* oacc, float& mrow, fv4& lrowC) {
    const int q_my = q0x + wid * 16 + l15;
    fv4 st[4] = {};
    __builtin_amdgcn_s_setprio(1);
#pragma unroll
    for (int ks = 0; ks < 2; ++ks)
#pragma unroll
      for (int jt = 0; jt < 4; ++jt)
        st[jt] = mfma16(kf[ks][jt], qf[ks], st[jt]);
    __builtin_amdgcn_s_setprio(0);

    // mask + max on RAW scores (SC > 0 so max commutes with the scale)
    float sr[4][4];
    float mloc = -1e30f;
    const int jb = j0 + 4 * g;
    if (j0 + 63 > q0x + wid * 16) {   // diagonal tile
#pragma unroll
      for (int jt = 0; jt < 4; ++jt)
#pragma unroll
        for (int r = 0; r < 4; ++r) {
          int j = jb + jt * 16 + r;
          float s = (j <= q_my) ? st[jt][r] : -1e30f;
          sr[jt][r] = s;
          mloc = fmaxf(mloc, s);
        }
    } else {                          // interior: fully visible
#pragma unroll
      for (int jt = 0; jt < 4; ++jt)
#pragma unroll
        for (int r = 0; r < 4; ++r) {
          sr[jt][r] = st[jt][r];
          mloc = fmaxf(mloc, st[jt][r]);
        }
    }
    mloc = fmaxf(mloc, __shfl_xor(mloc, 16));
    mloc = fmaxf(mloc, __shfl_xor(mloc, 32));
    mloc *= SC;                        // scaled row max (log2 domain)
    bool defer = __all(mloc <= mrow + 8.f);   // T13
    if (!defer) {
      float mnew = fmaxf(mrow, mloc);
      float sfac = exp2f(mrow - mnew);
      mrow = mnew;
      float sfC[4];
#pragma unroll
      for (int r = 0; r < 4; ++r) sfC[r] = __shfl(sfac, g * 4 + r);
#pragma unroll
      for (int dt = 0; dt < 4; ++dt)
#pragma unroll
        for (int r = 0; r < 4; ++r) oacc[dt][r] *= sfC[r];
#pragma unroll
      for (int r = 0; r < 4; ++r) lrowC[r] *= sfC[r];
    }
    float p[4][4];
#pragma unroll
    for (int jt = 0; jt < 4; ++jt)
#pragma unroll
      for (int r = 0; r < 4; ++r)
        p[jt][r] = exp2f(fmaf(sr[jt][r], SC, -mrow));

    // PV + row-sum via MFMA (pa slot (g,i) <-> logical j matching permuted V)
    __builtin_amdgcn_s_setprio(1);
    fv4 racc = {};
#pragma unroll
    for (int ks = 0; ks < 2; ++ks) {
      uv4 w;
      w[0] = cvtpk(p[ks][0], p[ks][1]);
      w[1] = cvtpk(p[ks][2], p[ks][3]);
      w[2] = cvtpk(p[ks + 2][0], p[ks + 2][1]);
      w[3] = cvtpk(p[ks + 2][2], p[ks + 2][3]);
      bh8 pa = __builtin_bit_cast(bh8, w);
      racc = mfma16(pa, ONES, racc);
#pragma unroll
      for (int dt = 0; dt < 4; ++dt)
        oacc[dt] = mfma16(pa, vf[ks][dt], oacc[dt]);
    }
    __builtin_amdgcn_s_setprio(0);
#pragma unroll
    for (int r = 0; r < 4; ++r) lrowC[r] += racc[r];
  };

  for (int rd = 0; rd < nrounds; ++rd) {
    __syncthreads();  // drains staging for buf[rd&1]; joins all waves
    int rem = nktB - (rd + 1) * 2;
    if (rem > 0) stage((rd + 1) & 1, (rd + 1) * 128, rem > 1 ? 2 : 1);
#pragma unroll
    for (int s = 0; s < 2; ++s) {
      int kt = rd * 2 + s;
      if (kt >= nktB) break;
      const int j0 = kt * 64;
      const u16* Kc = Ks[rd & 1][s];
      const u16* Vc = Vs[rd & 1][s];
      bh8 kf[2][4], vf[2][4];
#pragma unroll
      for (int ks = 0; ks < 2; ++ks) {
        int b8 = ks * 4 + g;
#pragma unroll
        for (int jt = 0; jt < 4; ++jt)
          kf[ks][jt] = lds_frag(Kc, jt * 16 + l15, b8);
#pragma unroll
        for (int dt = 0; dt < 4; ++dt)
          vf[ks][dt] = lds_frag(Vc, dt * 16 + l15, b8);
      }
      process(kf, vf, j0, qb0, qfB, oaccB, mB, lB);
      if (kt <= ia) process(kf, vf, j0, qa0, qfA, oaccA, mA, lA);
    }
  }

  auto wout = [&](fv4* oacc, fv4 lrowC, int q0x) {
#pragma unroll
    for (int dt = 0; dt < 4; ++dt)
#pragma unroll
      for (int r = 0; r < 4; ++r) {
        int row = q0x + wid * 16 + g * 4 + r;
        int col = dt * 16 + l15;
        ob[((size_t)b * S + row) * 1024 + h * 64 + col] =
            f2b(oacc[dt][r] / lrowC[r]);
      }
  };
  wout(oaccA, lA, qa0);
  wout(oaccB, lB, qb0);
}

// ---------------------------------------------------------------------------
// Gate + fused ffn-rmsnorm: computes top-2 AND writes hf_b = bf16(rmsnorm).
// ---------------------------------------------------------------------------
__global__ __launch_bounds__(256) void gate_topk(
    const float* __restrict__ x2, const float* __restrict__ nw,
    const float* __restrict__ gw, const float* __restrict__ gb,
    int* __restrict__ topk_e, float* __restrict__ topk_w,
    u16* __restrict__ hf) {
  int t = blockIdx.x * 4 + (threadIdx.x >> 6);
  int lane = threadIdx.x & 63;
  const float* xr = x2 + (size_t)t * 1024;
  float hv[16];
  float ss = 0.f;
#pragma unroll
  for (int i = 0; i < 4; ++i) {
    fv4 v = *(const fv4*)(xr + lane * 16 + i * 4);
#pragma unroll
    for (int j = 0; j < 4; ++j) {
      hv[i * 4 + j] = v[j];
      ss += v[j] * v[j];
    }
  }
#pragma unroll
  for (int off = 1; off < 64; off <<= 1) ss += __shfl_xor(ss, off);
  float inv = rsqrtf(ss * (1.0f / 1024.f) + 1e-6f);
  const fv4* nwp = (const fv4*)(nw + lane * 16);
#pragma unroll
  for (int i = 0; i < 4; ++i) {
    fv4 wv = nwp[i];
#pragma unroll
    for (int j = 0; j < 4; ++j) hv[i * 4 + j] *= inv * wv[j];
  }
  {  // fused rmsnorm output
    bh8 o0, o1;
#pragma unroll
    for (int j = 0; j < 8; ++j) {
      o0[j] = (short)f2b(hv[j]);
      o1[j] = (short)f2b(hv[8 + j]);
    }
    u16* hp = hf + (size_t)t * 1024 + lane * 16;
    *(bh8*)hp = o0;
    *(bh8*)(hp + 8) = o1;
  }
  float logit[8];
#pragma unroll
  for (int e = 0; e < 8; ++e) {
    const fv4* wp = (const fv4*)(gw + (size_t)e * 1024 + lane * 16);
    float s = 0.f;
#pragma unroll
    for (int i = 0; i < 4; ++i) {
      fv4 wv = wp[i];
#pragma unroll
      for (int j = 0; j < 4; ++j) s += hv[i * 4 + j] * wv[j];
    }
    logit[e] = s;
  }
#pragma unroll
  for (int off = 1; off < 64; off <<= 1)
#pragma unroll
    for (int e = 0; e < 8; ++e) logit[e] += __shfl_xor(logit[e], off);
  if (lane == 0) {
#pragma unroll
    for (int e = 0; e < 8; ++e) logit[e] += gb[e];
    float mx = logit[0];
#pragma unroll
    for (int e = 1; e < 8; ++e) mx = fmaxf(mx, logit[e]);
    float pe[8], se = 0.f;
#pragma unroll
    for (int e = 0; e < 8; ++e) { pe[e] = __expf(logit[e] - mx); se += pe[e]; }
    float rs = 1.f / se;
#pragma unroll
    for (int e = 0; e < 8; ++e) pe[e] *= rs;
    int i0 = 0;
    float b0 = pe[0];
#pragma unroll
    for (int e = 1; e < 8; ++e)
      if (pe[e] > b0) { b0 = pe[e]; i0 = e; }
    int i1 = -1;
    float b1v = -1.f;
#pragma unroll
    for (int e = 0; e < 8; ++e)
      if (e != i0 && pe[e] > b1v) { b1v = pe[e]; i1 = e; }
    topk_e[2 * t] = i0;
    topk_e[2 * t + 1] = i1;
    topk_w[2 * t] = b0;
    topk_w[2 * t + 1] = b1v;
  }
}

// One block, 8 waves: wave e ballot-ranks its tokens (deterministic order),
// thread 0 builds the padded tile map, then all threads fill rowid[2T]
// (compact row index of each token's two expert outputs).
__global__ __launch_bounds__(512) void route_tokens(
    const int* __restrict__ topk_e, int* __restrict__ pos_of,
    int* __restrict__ etok, int* __restrict__ meta, int* __restrict__ rowid,
    int T2) {
  __shared__ int scnt[8], sbase[8];
  const int e = threadIdx.x >> 6;
  const int lane = threadIdx.x & 63;
  int base = 0;
  for (int i0 = 0; i0 < T2; i0 += 128) {
    iv2 te = *(const iv2*)(topk_e + i0 + lane * 2);
    unsigned long long m0 = __ballot(te[0] == e);
    unsigned long long m1 = __ballot(te[1] == e);
    unsigned long long lt = (1ull << lane) - 1;
    int pre = __popcll(m0 & lt) + __popcll(m1 & lt);
    if (te[0] == e) {
      int pos = base + pre;
      etok[e * 4096 + pos] = (i0 >> 1) + lane;
      pos_of[i0 + lane * 2] = pos;
      ++pre;
    }
    if (te[1] == e) {
      int pos = base + pre;
      etok[e * 4096 + pos] = (i0 >> 1) + lane;
      pos_of[i0 + lane * 2 + 1] = pos;
    }
    base += __popcll(m0) + __popcll(m1);
  }
  if (lane == 0) scnt[e] = base;
  __syncthreads();
  if (threadIdx.x == 0) {
    int tt = 0, rb = 0;
#pragma unroll
    for (int e2 = 0; e2 < 8; ++e2) {
      sbase[e2] = rb;
      int c = scnt[e2];
      int nt = (c + 127) >> 7;
      for (int i = 0; i < nt; ++i) {
        meta[16 + tt * 4] = e2;
        meta[17 + tt * 4] = i * 128;
        meta[18 + tt * 4] = c;
        meta[19 + tt * 4] = rb + i * 128;
        ++tt;
      }
      rb += nt * 128;
    }
    meta[0] = tt;
  }
  __syncthreads();
  for (int i = threadIdx.x; i < T2; i += 512)
    rowid[i] = sbase[topk_e[i]] + pos_of[i];
}

// ---------------------------------------------------------------------------
extern "C" void kernel_launch(void* const* d_in, const int* in_sizes, int n_in,
                              void* d_out, int out_size, void* d_ws,
                              size_t ws_size, hipStream_t stream) {
  (void)in_sizes; (void)n_in; (void)out_size; (void)ws_size;
  const int Sc = 2048, Dc = 1024, NHc = 16, Tc = 4096, SH = 2048;

  const float* x   = (const float*)d_in[0];
  const float* fc  = (const float*)d_in[1];
  const float* fs  = (const float*)d_in[2];
  const float* wq  = (const float*)d_in[4];
  const float* wk  = (const float*)d_in[5];
  const float* wv  = (const float*)d_in[6];
  const float* wo  = (const float*)d_in[7];
  const float* anw = (const float*)d_in[8];
  const float* fnw = (const float*)d_in[9];
  const float* gw  = (const float*)d_in[10];
  const float* gb  = (const float*)d_in[11];
  const float* w1  = (const float*)d_in[12];
  const float* b1  = (const float*)d_in[13];
  const float* w2  = (const float*)d_in[14];
  const float* b2  = (const float*)d_in[15];
  const float* w3  = (const float*)d_in[16];
  const float* b3  = (const float*)d_in[17];
  const float* sgw = (const float*)d_in[18];
  const float* suw = (const float*)d_in[19];
  const float* sdw = (const float*)d_in[20];
  float* out = (float*)d_out;

  char* base = (char*)d_ws;
  size_t off = 0;
  auto alloc = [&](size_t bytes) -> void* {
    void* p = base + off;
    off += (bytes + 255) & ~(size_t)255;
    return p;
  };
  // weights: wqkv+wo FIRST (their region is reused as hf_b after wo-gemm)
  u16* wqkv_b = (u16*)alloc(2ull * 3072 * 1024);     // 6.29 MB
  u16* wo_b   = (u16*)alloc(2ull * 1024 * 1024);     // 2.10 MB
  u16* sgu_b  = (u16*)alloc(2ull * 4096 * 1024);     // 8.39 MB (interleaved)
  u16* sdw_b  = (u16*)alloc(2ull * 1024 * 2048);     // 4.19 MB
  u16* w13_b  = (u16*)alloc(2ull * 8 * 2048 * 1024); // 33.6 MB (interleaved)
  u16* w2_b   = (u16*)alloc(2ull * 8 * 1024 * 1024); // 16.8 MB
  // region A: qkv_out (25.2) -> eo (18.6)
  char* regA = (char*)alloc(2ull * Tc * 4096);
  // region B: h_b/qr/kr/vt/o_b (33.6) -> a13 (18.6)
  char* regB = (char*)alloc(2ull * (size_t)MAX_TILES * 128 * 2048);
  float* x2  = (float*)alloc(4ull * Tc * Dc);        // 16.8 MB
  u16* hs_b  = (u16*)alloc(2ull * Tc * SH);          // 16.8 MB
  int* topk_e = (int*)alloc(2ull * Tc * 4);
  float* topk_w = (float*)alloc(2ull * Tc * 4);
  int* pos_of = (int*)alloc(2ull * Tc * 4);
  int* rowid = (int*)alloc(2ull * Tc * 4);
  int* etok = (int*)alloc(8ull * 4096 * 4);
  int* meta = (int*)alloc(512 * 4);

  u16* qkv_out = (u16*)regA;
  u16* eo_c    = (u16*)regA;
  u16* h_b  = (u16*)regB;
  u16* qr   = (u16*)regB;
  u16* kr   = (u16*)(regB + 2ull * Tc * Dc);
  u16* vt_  = (u16*)(regB + 4ull * Tc * Dc);
  u16* o_b  = (u16*)(regB + 6ull * Tc * Dc);
  u16* a13_c = (u16*)regB;
  u16* hf_b = wqkv_b;  // overlays wqkv+wo after attention branch done

  // ---- prep: all converts + first rmsnorm in one dispatch ----
  mega_prep<<<dim3(21504), 256, 0, stream>>>(
      wq, wk, wv, wo, sdw, w2, sgw, suw, w1, w3, x, anw, wqkv_b, wo_b, sdw_b,
      w2_b, sgu_b, w13_b, h_b);

  // ---- attention branch ----
  gemm_bt<0, 128, 1><<<dim3(3072 / 128, Tc / 128), 512, 0, stream>>>(
      h_b, wqkv_b, Tc, 3072, Dc, qkv_out, nullptr, nullptr, nullptr, nullptr,
      nullptr, nullptr);
  rope_repack<<<dim3(Sc / 64, 2, 4), 256, 0, stream>>>(qkv_out, fc, fs, qr, kr,
                                                       vt_, Sc);
  attn_fwd<<<dim3(2 * NHc, Sc / 128), 256, 0, stream>>>(qr, kr, vt_, o_b, Sc,
                                                        NHc);
  gemm_bt<1, 64, 1><<<dim3(Dc / 128, Tc / 64), 512, 0, stream>>>(
      o_b, wo_b, Tc, Dc, Dc, nullptr, x2, x, nullptr, nullptr, nullptr,
      nullptr);

  // ---- ffn branch ----
  gate_topk<<<Tc / 4, 256, 0, stream>>>(x2, fnw, gw, gb, topk_e, topk_w,
                                        hf_b);
  route_tokens<<<1, 512, 0, stream>>>(topk_e, pos_of, etok, meta, rowid,
                                      2 * Tc);

  // merged: shared-expert gate|up (silu epilogue -> hs) + MoE w13 gather
  gemm_sgu_w13<<<dim3(1024 + 16 * MAX_TILES), 512, 0, stream>>>(
      hf_b, sgu_b, hs_b, w13_b, a13_c, b1, b3, meta, etok);

  // MoE w2 (TM=64 half-tiles)
  gemm_bt<6, 64><<<dim3(Dc / 128, 2 * MAX_TILES), 512, 0, stream>>>(
      a13_c, w2_b, /*lda=*/1024, Dc, 1024, eo_c, nullptr, nullptr, nullptr,
      b2, meta, etok);

  // final: out = x2 + hs @ sdw^T + w0*eo[r0] + w1*eo[r1]
  gemm_bt<9, 64, 1><<<dim3(Dc / 128, Tc / 64), 512, 0, stream>>>(
      hs_b, sdw_b, Tc, Dc, SH, eo_c, out, x2, nullptr, topk_w, rowid,
      nullptr);
}

// Round 14
// 358.415 us; speedup vs baseline: 1.1113x; 1.0136x over previous
//
#include <hip/hip_runtime.h>

// ---------------------------------------------------------------------------
// TransformerBlock on MI355X (gfx950), round 14:
//  - RoPE fused into the qkv GEMM epilogue (MODE 10): rotation partner is in
//    lane^1 of the C-fragment -> one shfl_xor + fmaf; q/k written directly in
//    rotated head-major layout. Slim rope_v kernel only transposes V.
//    Saves ~34MB of HBM round-trip.
//  - GEMMs: 512-thread / 8-wave blocks, BK=64, dbuf, depth-1 counted vmcnt,
//    raw barriers, XCD-chunk + 2D supertile ordering.
//  - mega_prep (all converts + rmsnorm), paired-q-tile attention (KVBLK=128),
//    atomic-free routing, fused epilogues unchanged.
// ---------------------------------------------------------------------------

typedef unsigned short u16;
typedef __attribute__((ext_vector_type(8))) short bh8;   // 8 x bf16
typedef __attribute__((ext_vector_type(4))) float fv4;
typedef __attribute__((ext_vector_type(4))) unsigned uv4;
typedef __attribute__((ext_vector_type(2))) int iv2;

#define LOG2E 1.4426950408889634f
#define MAX_TILES 71

__device__ __forceinline__ float b2f(u16 u) {
  return __builtin_bit_cast(float, ((unsigned)u) << 16);
}
__device__ __forceinline__ u16 f2b(float f) {
  unsigned x = __builtin_bit_cast(unsigned, f);
  return (u16)((x + 0x7fffu + ((x >> 16) & 1u)) >> 16);  // RNE
}
__device__ __forceinline__ fv4 mfma16(bh8 a, bh8 b, fv4 c) {
  return __builtin_amdgcn_mfma_f32_16x16x32_bf16(a, b, c, 0, 0, 0);
}
__device__ __forceinline__ unsigned cvtpk(float lo, float hi) {
  unsigned r;
  asm("v_cvt_pk_bf16_f32 %0, %1, %2" : "=v"(r) : "v"(lo), "v"(hi));
  return r;
}

// Bijective XCD-chunk swizzle (m204).
__device__ __forceinline__ int xcd_swizzle1d(int flat, int nwg) {
  int q = nwg >> 3, r = nwg & 7;
  int xcd = flat & 7, idx = flat >> 3;
  return (xcd < r ? xcd * (q + 1) : r * (q + 1) + (xcd - r) * q) + idx;
}

#define GLD16(g, l)                                                        \
  __builtin_amdgcn_global_load_lds(                                        \
      (const __attribute__((address_space(1))) void*)(g),                  \
      (__attribute__((address_space(3))) void*)(l), 16, 0, 0)

// Read one MFMA fragment (16B) from a [rows][64] bf16 LDS tile whose rows are
// 128B and whose 16B blocks are XOR-swizzled by (row&7).
__device__ __forceinline__ bh8 lds_frag(const u16* base, int row, int b8) {
  int off = row * 128 + ((b8 * 16) ^ ((row & 7) << 4));
  return *(const bh8*)((const char*)base + off);
}

// ---------------------------------------------------------------------------
// Shared GEMM body (512 threads, 8 waves, wave grid 2x4):
// C[M,N] = A[M,K] (bf16) @ B[N,K]^T (bf16), f32 accumulate.
// TM: A-tile rows (128 or 64). B-tile is 128 cols. Per-wave out: (TM/2)x32.
// MODE 1: Cf = add1 + gemm
// MODE 6: compact-A grouped MoE (w2): lda via M; Cb = bf16(gemm + bias_e)
//         (TM=64: by encodes tile*2+half)
// MODE 7: interleaved silu (shared expert): Cb[.,N/2] = silu(g)*u
// MODE 8: gather-A grouped MoE w13, interleaved silu + biases
// MODE 9: final: Cf = add1 + gemm + w0*eo[r0] + w1*eo[r1]
// MODE 10: qkv with fused RoPE: cols<1024 -> rotated q (Cb=qr head-major);
//          1024..2047 -> rotated k (Cf cast = kr); >=2048 -> vbuf (bias cast).
//          add1=freq_cos, add2=freq_sin. Rotation partner via shfl_xor(x,1).
// K-loop: BK=64, dbuf, depth-1 prefetch, counted vmcnt, raw barriers.
// ---------------------------------------------------------------------------
template <int MODE, int TM>
__device__ __forceinline__ void gemm_body(
    u16* AsB, u16* BsB, int bx, int by, const u16* __restrict__ A,
    const u16* __restrict__ B, int M, int N, int K, u16* __restrict__ Cb,
    float* __restrict__ Cf, const float* __restrict__ add1,
    const float* __restrict__ add2, const float* __restrict__ bias,
    const int* __restrict__ tmeta, const int* __restrict__ etok) {
  constexpr int MR = TM / 32;   // M-frags per wave: 128->4, 64->2
  constexpr int ACL = TM / 64;  // A-chunks per thread: 128->2, 64->1
  const int lane = threadIdx.x & 63;
  const int wid = threadIdx.x >> 6;       // 0..7
  const int wr = wid >> 2, wc = wid & 3;  // wave grid 2x4
  const int n0 = bx * 128;
  const int l15 = lane & 15;
  const int rr = lane >> 3;
  const int b8s = (lane & 7) ^ rr;
  const int ldA = (MODE == 6) ? M : K;

  int m0 = 0, e = 0, m0l = 0, cnt = 0, row0 = 0;
  const u16* Bp = B;
  if constexpr (MODE == 6 || MODE == 8) {
    int tile = by, half = 0;
    if constexpr (MODE == 6 && TM == 64) {
      tile = by >> 1;
      half = by & 1;
    }
    if (tile >= tmeta[0]) return;
    e = tmeta[16 + tile * 4];
    m0l = tmeta[17 + tile * 4];
    cnt = tmeta[18 + tile * 4];
    row0 = tmeta[19 + tile * 4] + half * 64;
    Bp = B + (size_t)e * N * K;
  } else {
    m0 = by * TM;
  }

  const u16* Arow[ACL];
  const u16* Brow[2];
#pragma unroll
  for (int i = 0; i < ACL; ++i) {
    int c = wid * ACL + i;
    int row = c * 8 + rr;
    if constexpr (MODE == 8) {
      int li = m0l + row;
      li = li < cnt ? li : cnt - 1;
      int tok = etok[e * 4096 + li];
      Arow[i] = A + (size_t)tok * ldA + b8s * 8;
    } else if constexpr (MODE == 6) {
      Arow[i] = A + (size_t)(row0 + row) * ldA + b8s * 8;
    } else {
      Arow[i] = A + (size_t)(m0 + row) * ldA + b8s * 8;
    }
  }
#pragma unroll
  for (int i = 0; i < 2; ++i)
    Brow[i] = Bp + (size_t)(n0 + (wid * 2 + i) * 8 + rr) * K + b8s * 8;

  fv4 acc[MR][2] = {};
  const int nt = K >> 6;

  // prologue: stage tile 0 into buffer 0
#pragma unroll
  for (int i = 0; i < ACL; ++i)
    GLD16(Arow[i], &AsB[(wid * ACL + i) * 512]);
#pragma unroll
  for (int i = 0; i < 2; ++i)
    GLD16(Brow[i], &BsB[(wid * 2 + i) * 512]);

  for (int t = 0; t < nt; ++t) {
    const int cur = t & 1;
    u16* Asc = AsB + cur * (TM * 64);
    u16* Bsc = BsB + cur * (128 * 64);
    if (t + 1 < nt) {
      const int k0 = (t + 1) * 64;
      u16* Asn = AsB + (cur ^ 1) * (TM * 64);
      u16* Bsn = BsB + (cur ^ 1) * (128 * 64);
#pragma unroll
      for (int i = 0; i < ACL; ++i)
        GLD16(Arow[i] + k0, &Asn[(wid * ACL + i) * 512]);
#pragma unroll
      for (int i = 0; i < 2; ++i)
        GLD16(Brow[i] + k0, &Bsn[(wid * 2 + i) * 512]);
      // wait only for the OLDEST (cur-tile) loads; next-tile stays in flight
      if constexpr (ACL == 2)
        asm volatile("s_waitcnt vmcnt(4)" ::: "memory");
      else
        asm volatile("s_waitcnt vmcnt(3)" ::: "memory");
    } else {
      asm volatile("s_waitcnt vmcnt(0)" ::: "memory");
    }
    __builtin_amdgcn_s_barrier();          // buf[cur] visible to all waves
    __builtin_amdgcn_sched_barrier(0);     // pin ds_reads below barrier

#pragma unroll
    for (int ks = 0; ks < 2; ++ks) {
      int b8 = ks * 4 + (lane >> 4);
      bh8 af[MR], bf[2];
#pragma unroll
      for (int mi = 0; mi < MR; ++mi)
        af[mi] = lds_frag(Asc, wr * (16 * MR) + mi * 16 + l15, b8);
      if constexpr (MODE == 7 || MODE == 8) {
        int col0 = (wc >> 1) * 64 + (wc & 1) * 16;
        bf[0] = lds_frag(Bsc, col0 + l15, b8);
        bf[1] = lds_frag(Bsc, col0 + 32 + l15, b8);
      } else {
#pragma unroll
        for (int ni = 0; ni < 2; ++ni)
          bf[ni] = lds_frag(Bsc, wc * 32 + ni * 16 + l15, b8);
      }
      __builtin_amdgcn_s_setprio(1);
#pragma unroll
      for (int mi = 0; mi < MR; ++mi)
#pragma unroll
        for (int ni = 0; ni < 2; ++ni)
          acc[mi][ni] = mfma16(af[mi], bf[ni], acc[mi][ni]);
      __builtin_amdgcn_s_setprio(0);
    }
    __builtin_amdgcn_sched_barrier(0);     // pin reads above barrier
    __builtin_amdgcn_s_barrier();          // all waves done reading buf[cur]
    __builtin_amdgcn_sched_barrier(0);     // pin next stage below barrier
  }

  const int rbase = (MODE == 6 || MODE == 8) ? row0 : m0;
  const int r0b = rbase + wr * (16 * MR) + (lane >> 4) * 4;

  if constexpr (MODE == 7 || MODE == 8) {
    const int OUTN = N >> 1;
    const int c = (n0 >> 1) + (wc >> 1) * 32 + (wc & 1) * 16 + l15;
    const float* bb1 = nullptr;
    const float* bb3 = nullptr;
    if constexpr (MODE == 8) {
      bb1 = add1 + (size_t)e * OUTN;
      bb3 = add2 + (size_t)e * OUTN;
    }
#pragma unroll
    for (int mi = 0; mi < MR; ++mi) {
#pragma unroll
      for (int r = 0; r < 4; ++r) {
        int row = r0b + mi * 16 + r;
        float xg = acc[mi][0][r];
        float yu = acc[mi][1][r];
        if constexpr (MODE == 8) {
          xg += bb1[c];
          yu += bb3[c];
        }
        float s = xg / (1.f + __expf(-xg));
        Cb[(size_t)row * OUTN + c] = f2b(s * yu);
      }
    }
  } else if constexpr (MODE == 9) {
    const int c0b = n0 + wc * 32 + l15;
#pragma unroll
    for (int mi = 0; mi < MR; ++mi) {
#pragma unroll
      for (int r = 0; r < 4; ++r) {
        int row = r0b + mi * 16 + r;
        int g0 = tmeta[2 * row], g1 = tmeta[2 * row + 1];
        float w0 = bias[2 * row], w1 = bias[2 * row + 1];
        const u16* e0p = Cb + (size_t)g0 * 1024;
        const u16* e1p = Cb + (size_t)g1 * 1024;
#pragma unroll
        for (int ni = 0; ni < 2; ++ni) {
          int c = c0b + ni * 16;
          size_t idx = (size_t)row * N + c;
          Cf[idx] = add1[idx] + acc[mi][ni][r] + w0 * b2f(e0p[c]) +
                    w1 * b2f(e1p[c]);
        }
      }
    }
  } else if constexpr (MODE == 10) {
    // fused RoPE qkv epilogue. Block is entirely within q / k / v region
    // (region boundaries are 128-aligned). Partner element (col^1) is held
    // by lane^1 in the same fragment position.
    const int c0b = n0 + wc * 32 + l15;
    u16* vbuf = (u16*)bias;
    u16* kr = (u16*)Cf;
#pragma unroll
    for (int mi = 0; mi < MR; ++mi) {
#pragma unroll
      for (int ni = 0; ni < 2; ++ni) {
        int c = c0b + ni * 16;
#pragma unroll
        for (int r = 0; r < 4; ++r) {
          int row = r0b + mi * 16 + r;
          float x = acc[mi][ni][r];
          float p = __shfl_xor(x, 1);
          if (c < 2048) {
            int cc = c & 1023;
            int i = (cc & 63) >> 1;
            int s = row & 2047, bb = row >> 11;
            float co = add1[s * 32 + i], si = add2[s * 32 + i];
            float o = fmaf(p, (c & 1) ? si : -si, x * co);
            u16* dst = (c < 1024) ? Cb : kr;
            dst[((size_t)((bb * 16 + (cc >> 6)) * 2048 + s)) * 64 +
                (cc & 63)] = f2b(o);
          } else {
            vbuf[(size_t)row * 1024 + (c - 2048)] = f2b(x);
          }
        }
      }
    }
  } else {
    const int c0b = n0 + wc * 32 + l15;
    const float* bb = nullptr;
    if constexpr (MODE == 6) bb = bias + (size_t)e * N;
#pragma unroll
    for (int mi = 0; mi < MR; ++mi) {
#pragma unroll
      for (int ni = 0; ni < 2; ++ni) {
        int c = c0b + ni * 16;
#pragma unroll
        for (int r = 0; r < 4; ++r) {
          int row = r0b + mi * 16 + r;
          size_t idx = (size_t)row * N + c;
          float v = acc[mi][ni][r];
          if constexpr (MODE == 0) Cb[idx] = f2b(v);
          else if constexpr (MODE == 1) Cf[idx] = add1[idx] + v;
          else Cb[idx] = f2b(v + bb[c]);
        }
      }
    }
  }
}

// STILE=1: decode the (XCD-chunked) flat index as 8by x 4bx supertiles.
template <int MODE, int TM = 128, int STILE = 0>
__global__ __launch_bounds__(512) void gemm_bt(
    const u16* __restrict__ A, const u16* __restrict__ B, int M, int N, int K,
    u16* __restrict__ Cb, float* __restrict__ Cf,
    const float* __restrict__ add1, const float* __restrict__ add2,
    const float* __restrict__ bias, const int* __restrict__ tmeta,
    const int* __restrict__ etok) {
  __shared__ u16 As[2][TM * 64];
  __shared__ u16 Bs[2][128 * 64];
  const int gx = gridDim.x;
  int flat = (int)blockIdx.y * gx + (int)blockIdx.x;
  flat = xcd_swizzle1d(flat, gx * (int)gridDim.y);
  int bx, by;
  if constexpr (STILE) {
    int SX = gx >> 2;
    int sidx = flat >> 5, within = flat & 31;
    int sy = sidx / SX, sx = sidx - sy * SX;
    by = sy * 8 + (within >> 2);
    bx = sx * 4 + (within & 3);
  } else {
    by = flat / gx;
    bx = flat - by * gx;
  }
  gemm_body<MODE, TM>(&As[0][0], &Bs[0][0], bx, by, A, B, M, N, K, Cb, Cf,
                      add1, add2, bias, tmeta, etok);
}

// Merged shared-expert (MODE 7, supertiled 32x32) + MoE w13 (MODE 8).
__global__ __launch_bounds__(512) void gemm_sgu_w13(
    const u16* __restrict__ hf, const u16* __restrict__ sgu_w,
    u16* __restrict__ hs, const u16* __restrict__ w13_w,
    u16* __restrict__ a13, const float* __restrict__ b1,
    const float* __restrict__ b3, const int* __restrict__ meta,
    const int* __restrict__ etok) {
  __shared__ u16 As[2][128 * 64];
  __shared__ u16 Bs[2][128 * 64];
  const int nwg = 1024 + 16 * MAX_TILES;
  int flat = xcd_swizzle1d((int)blockIdx.x, nwg);
  if (flat < 1024) {
    // supertile decode: gx=32 (SX=8), gy=32
    int sidx = flat >> 5, within = flat & 31;
    int sy = sidx >> 3, sx = sidx & 7;
    int by = sy * 8 + (within >> 2);
    int bx = sx * 4 + (within & 3);
    gemm_body<7, 128>(&As[0][0], &Bs[0][0], bx, by, hf, sgu_w, 4096, 4096,
                      1024, hs, nullptr, nullptr, nullptr, nullptr, nullptr,
                      nullptr);
  } else {
    int idx = flat - 1024;
    int by = idx >> 4, bx = idx & 15;
    gemm_body<8, 128>(&As[0][0], &Bs[0][0], bx, by, hf, w13_w, 4096, 2048,
                      1024, a13, nullptr, b1, b3, nullptr, meta, etok);
  }
}

// ---------------------------------------------------------------------------
// mega_prep: ALL weight conversions + first rmsnorm in ONE dispatch.
// ---------------------------------------------------------------------------
__device__ __forceinline__ void conv_plain(const float* src, u16* dst,
                                           int lb) {
  size_t i = ((size_t)lb * 256 + threadIdx.x) * 8;
  fv4 a = *(const fv4*)(src + i);
  fv4 b = *(const fv4*)(src + i + 4);
  bh8 o;
#pragma unroll
  for (int j = 0; j < 4; ++j) o[j] = (short)f2b(a[j]);
#pragma unroll
  for (int j = 0; j < 4; ++j) o[4 + j] = (short)f2b(b[j]);
  *(bh8*)(dst + i) = o;
}
__device__ __forceinline__ void conv_ilv(const float* src, u16* dst, int lb,
                                         int half, int seg_shift) {
  size_t i = ((size_t)lb * 256 + threadIdx.x) * 8;
  int r = (int)(i >> 10), col = (int)(i & 1023);
  int rl = r & ((1 << seg_shift) - 1), e = r >> seg_shift;
  int dstrow = (e << (seg_shift + 1)) + ((rl >> 5) << 6) + (rl & 31) +
               (half << 5);
  fv4 a = *(const fv4*)(src + i);
  fv4 b = *(const fv4*)(src + i + 4);
  bh8 o;
#pragma unroll
  for (int j = 0; j < 4; ++j) o[j] = (short)f2b(a[j]);
#pragma unroll
  for (int j = 0; j < 4; ++j) o[4 + j] = (short)f2b(b[j]);
  *(bh8*)(dst + (size_t)dstrow * 1024 + col) = o;
}

__global__ __launch_bounds__(256) void mega_prep(
    const float* __restrict__ wq, const float* __restrict__ wk,
    const float* __restrict__ wv, const float* __restrict__ wo,
    const float* __restrict__ sdw, const float* __restrict__ w2,
    const float* __restrict__ sgw, const float* __restrict__ suw,
    const float* __restrict__ w1, const float* __restrict__ w3,
    const float* __restrict__ x, const float* __restrict__ anw,
    u16* __restrict__ wqkv_b, u16* __restrict__ wo_b,
    u16* __restrict__ sdw_b, u16* __restrict__ w2_b,
    u16* __restrict__ sgu_b, u16* __restrict__ w13_b,
    u16* __restrict__ h_b) {
  __shared__ float red[4];
  const int bid = blockIdx.x;
  if (bid < 512) {
    conv_plain(wq, wqkv_b, bid);
  } else if (bid < 1024) {
    conv_plain(wk, wqkv_b + 1048576, bid - 512);
  } else if (bid < 1536) {
    conv_plain(wv, wqkv_b + 2097152, bid - 1024);
  } else if (bid < 2048) {
    conv_plain(wo, wo_b, bid - 1536);
  } else if (bid < 3072) {
    conv_plain(sdw, sdw_b, bid - 2048);
  } else if (bid < 7168) {
    conv_plain(w2, w2_b, bid - 3072);
  } else if (bid < 8192) {
    conv_ilv(sgw, sgu_b, bid - 7168, 0, 11);
  } else if (bid < 9216) {
    conv_ilv(suw, sgu_b, bid - 8192, 1, 11);
  } else if (bid < 13312) {
    conv_ilv(w1, w13_b, bid - 9216, 0, 10);
  } else if (bid < 17408) {
    conv_ilv(w3, w13_b, bid - 13312, 1, 10);
  } else {
    int t = bid - 17408;
    const float* xr = x + (size_t)t * 1024;
    fv4 v = *(const fv4*)(xr + threadIdx.x * 4);
    float ss = v[0] * v[0] + v[1] * v[1] + v[2] * v[2] + v[3] * v[3];
#pragma unroll
    for (int off = 1; off < 64; off <<= 1) ss += __shfl_xor(ss, off);
    int lane = threadIdx.x & 63, wid = threadIdx.x >> 6;
    if (lane == 0) red[wid] = ss;
    __syncthreads();
    float inv =
        rsqrtf((red[0] + red[1] + red[2] + red[3]) * (1.0f / 1024.f) + 1e-6f);
    u16* op = h_b + (size_t)t * 1024 + threadIdx.x * 4;
    const float* wp = anw + threadIdx.x * 4;
#pragma unroll
    for (int i = 0; i < 4; ++i) op[i] = f2b(v[i] * inv * wp[i]);
  }
}

// ---------------------------------------------------------------------------
// rope_v: V-only repack from vbuf [T,1024] -> vt [B,NH,64,S] (transposed AND
// column-permuted per 64-block: physical group pg=4ks+g holds logical j
// {16ks+4g+r, 16ks+32+4g+r}).  Grid: (S/64, B, NH/4).
// ---------------------------------------------------------------------------
__global__ __launch_bounds__(256) void rope_v(const u16* __restrict__ vbuf,
                                              u16* __restrict__ vt, int S) {
  __shared__ u16 tile[64][65];
  const int s0 = blockIdx.x * 64;
  const int b = blockIdx.y;
  const int h0 = blockIdx.z * 4;
  for (int hh = 0; hh < 4; ++hh) {
    int h = h0 + hh;
    __syncthreads();
    for (int cc = threadIdx.x; cc < 512; cc += 256) {
      int tl = cc >> 3, d8 = cc & 7;
      bh8 val = *(const bh8*)(vbuf + ((size_t)(b * S + s0 + tl)) * 1024 +
                              h * 64 + d8 * 8);
#pragma unroll
      for (int j = 0; j < 8; ++j) tile[tl][d8 * 8 + j] = (u16)val[j];
    }
    __syncthreads();
    for (int cc = threadIdx.x; cc < 512; cc += 256) {
      int d = cc >> 3, pg = cc & 7;
      int sbase = 16 * (pg >> 2) + 4 * (pg & 3);
      bh8 o;
#pragma unroll
      for (int j = 0; j < 8; ++j)
        o[j] = (short)tile[sbase + (j & 3) + ((j >> 2) << 5)][d];
      *(bh8*)(vt + ((size_t)((b * 16 + h) * 64 + d)) * S + s0 + pg * 8) = o;
    }
  }
}

// ---------------------------------------------------------------------------
// Flash attention (causal), paired q-tiles, KVBLK=128 staging, hoisted shared
// K/V frags, MFMA row-sum, fma-folded scale, defer-max.
// Grid: (B*NH, nq/2). 4 waves x 16 q-rows.
// ---------------------------------------------------------------------------
__global__ __launch_bounds__(256) void attn_fwd(
    const u16* __restrict__ qr, const u16* __restrict__ kr,
    const u16* __restrict__ vt, u16* __restrict__ ob, int S, int NHc) {
  __shared__ u16 Ks[2][2][64 * 64];
  __shared__ u16 Vs[2][2][64 * 64];   // V^T subtiles, column-permuted
  const int lane = threadIdx.x & 63;
  const int wid = threadIdx.x >> 6;
  const int g = lane >> 4;
  const int l15 = lane & 15;
  const int bh = blockIdx.x;
  const int ia = blockIdx.y;
  const int nq = S / 64;
  const int qa0 = ia * 64;                 // light q-tile
  const int qb0 = (nq - 1 - ia) * 64;      // heavy q-tile
  const int b = bh / NHc, h = bh % NHc;
  const u16* qbase = qr + (size_t)bh * S * 64;
  const u16* kb = kr + (size_t)bh * S * 64;
  const u16* vb = vt + (size_t)bh * 64 * S;
  const float SC = 0.015625f * LOG2E;  // both ref scales, log2 domain
  const int rr = lane >> 3;
  const int b8s = (lane & 7) ^ rr;

  bh8 ONES;
#pragma unroll
  for (int j = 0; j < 8; ++j) ONES[j] = (short)0x3f80;  // bf16 1.0

  bh8 qfA[2], qfB[2];
  {
    const u16* qp = qbase + (size_t)(qa0 + wid * 16 + l15) * 64 + g * 8;
    qfA[0] = *(const bh8*)qp;
    qfA[1] = *(const bh8*)(qp + 32);
    qp = qbase + (size_t)(qb0 + wid * 16 + l15) * 64 + g * 8;
    qfB[0] = *(const bh8*)qp;
    qfB[1] = *(const bh8*)(qp + 32);
  }
  fv4 oaccA[4] = {}, oaccB[4] = {};
  fv4 lA = {}, lB = {};                // row-sums, C-layout (row = 4g+r)
  float mA = -1e30f, mB = -1e30f;
  const int nktB = nq - ia;            // 64-wide kv tiles for heavy q-tile
  const int nrounds = (nktB + 1) >> 1; // 128-wide staging rounds

  auto stage = [&](int buf, int j0, int nsub) {
    for (int s = 0; s < nsub; ++s) {
#pragma unroll
      for (int i = 0; i < 2; ++i) {
        int c = wid * 2 + i;
        int row = c * 8 + rr;
        GLD16(kb + (size_t)(j0 + s * 64 + row) * 64 + b8s * 8,
              &Ks[buf][s][c * 512]);
        GLD16(vb + (size_t)row * S + j0 + s * 64 + b8s * 8,
              &Vs[buf][s][c * 512]);
      }
    }
  };
  stage(0, 0, nktB > 1 ? 2 : 1);

  auto process = [&](const bh8 (&kf)[2][4], const bh8 (&vf)[2][4], int j0,
                     int q0x, bh8* qf, fv4* oacc, float& mrow, fv4& lrowC) {
    const int q_my = q0x + wid * 16 + l15;
    fv4 st[4] = {};
    __builtin_amdgcn_s_setprio(1);
#pragma unroll
    for (int ks = 0; ks < 2; ++ks)
#pragma unroll
      for (int jt = 0; jt < 4; ++jt)
        st[jt] = mfma16(kf[ks][jt], qf[ks], st[jt]);
    __builtin_amdgcn_s_setprio(0);

    // mask + max on RAW scores (SC > 0 so max commutes with the scale)
    float sr[4][4];
    float mloc = -1e30f;
    const int jb = j0 + 4 * g;
    if (j0 + 63 > q0x + wid * 16) {   // diagonal tile
#pragma unroll
      for (int jt = 0; jt < 4; ++jt)
#pragma unroll
        for (int r = 0; r < 4; ++r) {
          int j = jb + jt * 16 + r;
          float s = (j <= q_my) ? st[jt][r] : -1e30f;
          sr[jt][r] = s;
          mloc = fmaxf(mloc, s);
        }
    } else {                          // interior: fully visible
#pragma unroll
      for (int jt = 0; jt < 4; ++jt)
#pragma unroll
        for (int r = 0; r < 4; ++r) {
          sr[jt][r] = st[jt][r];
          mloc = fmaxf(mloc, st[jt][r]);
        }
    }
    mloc = fmaxf(mloc, __shfl_xor(mloc, 16));
    mloc = fmaxf(mloc, __shfl_xor(mloc, 32));
    mloc *= SC;                        // scaled row max (log2 domain)
    bool defer = __all(mloc <= mrow + 8.f);   // T13
    if (!defer) {
      float mnew = fmaxf(mrow, mloc);
      float sfac = exp2f(mrow - mnew);
      mrow = mnew;
      float sfC[4];
#pragma unroll
      for (int r = 0; r < 4; ++r) sfC[r] = __shfl(sfac, g * 4 + r);
#pragma unroll
      for (int dt = 0; dt < 4; ++dt)
#pragma unroll
        for (int r = 0; r < 4; ++r) oacc[dt][r] *= sfC[r];
#pragma unroll
      for (int r = 0; r < 4; ++r) lrowC[r] *= sfC[r];
    }
    float p[4][4];
#pragma unroll
    for (int jt = 0; jt < 4; ++jt)
#pragma unroll
      for (int r = 0; r < 4; ++r)
        p[jt][r] = exp2f(fmaf(sr[jt][r], SC, -mrow));

    // PV + row-sum via MFMA (pa slot (g,i) <-> logical j matching permuted V)
    __builtin_amdgcn_s_setprio(1);
    fv4 racc = {};
#pragma unroll
    for (int ks = 0; ks < 2; ++ks) {
      uv4 w;
      w[0] = cvtpk(p[ks][0], p[ks][1]);
      w[1] = cvtpk(p[ks][2], p[ks][3]);
      w[2] = cvtpk(p[ks + 2][0], p[ks + 2][1]);
      w[3] = cvtpk(p[ks + 2][2], p[ks + 2][3]);
      bh8 pa = __builtin_bit_cast(bh8, w);
      racc = mfma16(pa, ONES, racc);
#pragma unroll
      for (int dt = 0; dt < 4; ++dt)
        oacc[dt] = mfma16(pa, vf[ks][dt], oacc[dt]);
    }
    __builtin_amdgcn_s_setprio(0);
#pragma unroll
    for (int r = 0; r < 4; ++r) lrowC[r] += racc[r];
  };

  for (int rd = 0; rd < nrounds; ++rd) {
    __syncthreads();  // drains staging for buf[rd&1]; joins all waves
    int rem = nktB - (rd + 1) * 2;
    if (rem > 0) stage((rd + 1) & 1, (rd + 1) * 128, rem > 1 ? 2 : 1);
#pragma unroll
    for (int s = 0; s < 2; ++s) {
      int kt = rd * 2 + s;
      if (kt >= nktB) break;
      const int j0 = kt * 64;
      const u16* Kc = Ks[rd & 1][s];
      const u16* Vc = Vs[rd & 1][s];
      bh8 kf[2][4], vf[2][4];
#pragma unroll
      for (int ks = 0; ks < 2; ++ks) {
        int b8 = ks * 4 + g;
#pragma unroll
        for (int jt = 0; jt < 4; ++jt)
          kf[ks][jt] = lds_frag(Kc, jt * 16 + l15, b8);
#pragma unroll
        for (int dt = 0; dt < 4; ++dt)
          vf[ks][dt] = lds_frag(Vc, dt * 16 + l15, b8);
      }
      process(kf, vf, j0, qb0, qfB, oaccB, mB, lB);
      if (kt <= ia) process(kf, vf, j0, qa0, qfA, oaccA, mA, lA);
    }
  }

  auto wout = [&](fv4* oacc, fv4 lrowC, int q0x) {
#pragma unroll
    for (int dt = 0; dt < 4; ++dt)
#pragma unroll
      for (int r = 0; r < 4; ++r) {
        int row = q0x + wid * 16 + g * 4 + r;
        int col = dt * 16 + l15;
        ob[((size_t)b * S + row) * 1024 + h * 64 + col] =
            f2b(oacc[dt][r] / lrowC[r]);
      }
  };
  wout(oaccA, lA, qa0);
  wout(oaccB, lB, qb0);
}

// ---------------------------------------------------------------------------
// Gate + fused ffn-rmsnorm: computes top-2 AND writes hf_b = bf16(rmsnorm).
// ---------------------------------------------------------------------------
__global__ __launch_bounds__(256) void gate_topk(
    const float* __restrict__ x2, const float* __restrict__ nw,
    const float* __restrict__ gw, const float* __restrict__ gb,
    int* __restrict__ topk_e, float* __restrict__ topk_w,
    u16* __restrict__ hf) {
  int t = blockIdx.x * 4 + (threadIdx.x >> 6);
  int lane = threadIdx.x & 63;
  const float* xr = x2 + (size_t)t * 1024;
  float hv[16];
  float ss = 0.f;
#pragma unroll
  for (int i = 0; i < 4; ++i) {
    fv4 v = *(const fv4*)(xr + lane * 16 + i * 4);
#pragma unroll
    for (int j = 0; j < 4; ++j) {
      hv[i * 4 + j] = v[j];
      ss += v[j] * v[j];
    }
  }
#pragma unroll
  for (int off = 1; off < 64; off <<= 1) ss += __shfl_xor(ss, off);
  float inv = rsqrtf(ss * (1.0f / 1024.f) + 1e-6f);
  const fv4* nwp = (const fv4*)(nw + lane * 16);
#pragma unroll
  for (int i = 0; i < 4; ++i) {
    fv4 wv = nwp[i];
#pragma unroll
    for (int j = 0; j < 4; ++j) hv[i * 4 + j] *= inv * wv[j];
  }
  {  // fused rmsnorm output
    bh8 o0, o1;
#pragma unroll
    for (int j = 0; j < 8; ++j) {
      o0[j] = (short)f2b(hv[j]);
      o1[j] = (short)f2b(hv[8 + j]);
    }
    u16* hp = hf + (size_t)t * 1024 + lane * 16;
    *(bh8*)hp = o0;
    *(bh8*)(hp + 8) = o1;
  }
  float logit[8];
#pragma unroll
  for (int e = 0; e < 8; ++e) {
    const fv4* wp = (const fv4*)(gw + (size_t)e * 1024 + lane * 16);
    float s = 0.f;
#pragma unroll
    for (int i = 0; i < 4; ++i) {
      fv4 wv = wp[i];
#pragma unroll
      for (int j = 0; j < 4; ++j) s += hv[i * 4 + j] * wv[j];
    }
    logit[e] = s;
  }
#pragma unroll
  for (int off = 1; off < 64; off <<= 1)
#pragma unroll
    for (int e = 0; e < 8; ++e) logit[e] += __shfl_xor(logit[e], off);
  if (lane == 0) {
#pragma unroll
    for (int e = 0; e < 8; ++e) logit[e] += gb[e];
    float mx = logit[0];
#pragma unroll
    for (int e = 1; e < 8; ++e) mx = fmaxf(mx, logit[e]);
    float pe[8], se = 0.f;
#pragma unroll
    for (int e = 0; e < 8; ++e) { pe[e] = __expf(logit[e] - mx); se += pe[e]; }
    float rs = 1.f / se;
#pragma unroll
    for (int e = 0; e < 8; ++e) pe[e] *= rs;
    int i0 = 0;
    float b0 = pe[0];
#pragma unroll
    for (int e = 1; e < 8; ++e)
      if (pe[e] > b0) { b0 = pe[e]; i0 = e; }
    int i1 = -1;
    float b1v = -1.f;
#pragma unroll
    for (int e = 0; e < 8; ++e)
      if (e != i0 && pe[e] > b1v) { b1v = pe[e]; i1 = e; }
    topk_e[2 * t] = i0;
    topk_e[2 * t + 1] = i1;
    topk_w[2 * t] = b0;
    topk_w[2 * t + 1] = b1v;
  }
}

// One block, 8 waves: wave e ballot-ranks its tokens (deterministic order),
// thread 0 builds the padded tile map, then all threads fill rowid[2T].
__global__ __launch_bounds__(512) void route_tokens(
    const int* __restrict__ topk_e, int* __restrict__ pos_of,
    int* __restrict__ etok, int* __restrict__ meta, int* __restrict__ rowid,
    int T2) {
  __shared__ int scnt[8], sbase[8];
  const int e = threadIdx.x >> 6;
  const int lane = threadIdx.x & 63;
  int base = 0;
  for (int i0 = 0; i0 < T2; i0 += 128) {
    iv2 te = *(const iv2*)(topk_e + i0 + lane * 2);
    unsigned long long m0 = __ballot(te[0] == e);
    unsigned long long m1 = __ballot(te[1] == e);
    unsigned long long lt = (1ull << lane) - 1;
    int pre = __popcll(m0 & lt) + __popcll(m1 & lt);
    if (te[0] == e) {
      int pos = base + pre;
      etok[e * 4096 + pos] = (i0 >> 1) + lane;
      pos_of[i0 + lane * 2] = pos;
      ++pre;
    }
    if (te[1] == e) {
      int pos = base + pre;
      etok[e * 4096 + pos] = (i0 >> 1) + lane;
      pos_of[i0 + lane * 2 + 1] = pos;
    }
    base += __popcll(m0) + __popcll(m1);
  }
  if (lane == 0) scnt[e] = base;
  __syncthreads();
  if (threadIdx.x == 0) {
    int tt = 0, rb = 0;
#pragma unroll
    for (int e2 = 0; e2 < 8; ++e2) {
      sbase[e2] = rb;
      int c = scnt[e2];
      int nt = (c + 127) >> 7;
      for (int i = 0; i < nt; ++i) {
        meta[16 + tt * 4] = e2;
        meta[17 + tt * 4] = i * 128;
        meta[18 + tt * 4] = c;
        meta[19 + tt * 4] = rb + i * 128;
        ++tt;
      }
      rb += nt * 128;
    }
    meta[0] = tt;
  }
  __syncthreads();
  for (int i = threadIdx.x; i < T2; i += 512)
    rowid[i] = sbase[topk_e[i]] + pos_of[i];
}

// ---------------------------------------------------------------------------
extern "C" void kernel_launch(void* const* d_in, const int* in_sizes, int n_in,
                              void* d_out, int out_size, void* d_ws,
                              size_t ws_size, hipStream_t stream) {
  (void)in_sizes; (void)n_in; (void)out_size; (void)ws_size;
  const int Sc = 2048, Dc = 1024, NHc = 16, Tc = 4096, SH = 2048;

  const float* x   = (const float*)d_in[0];
  const float* fc  = (const float*)d_in[1];
  const float* fs  = (const float*)d_in[2];
  const float* wq  = (const float*)d_in[4];
  const float* wk  = (const float*)d_in[5];
  const float* wv  = (const float*)d_in[6];
  const float* wo  = (const float*)d_in[7];
  const float* anw = (const float*)d_in[8];
  const float* fnw = (const float*)d_in[9];
  const float* gw  = (const float*)d_in[10];
  const float* gb  = (const float*)d_in[11];
  const float* w1  = (const float*)d_in[12];
  const float* b1  = (const float*)d_in[13];
  const float* w2  = (const float*)d_in[14];
  const float* b2  = (const float*)d_in[15];
  const float* w3  = (const float*)d_in[16];
  const float* b3  = (const float*)d_in[17];
  const float* sgw = (const float*)d_in[18];
  const float* suw = (const float*)d_in[19];
  const float* sdw = (const float*)d_in[20];
  float* out = (float*)d_out;

  char* base = (char*)d_ws;
  size_t off = 0;
  auto alloc = [&](size_t bytes) -> void* {
    void* p = base + off;
    off += (bytes + 255) & ~(size_t)255;
    return p;
  };
  // weights: wqkv+wo FIRST (their region is reused as hf_b after wo-gemm)
  u16* wqkv_b = (u16*)alloc(2ull * 3072 * 1024);     // 6.29 MB
  u16* wo_b   = (u16*)alloc(2ull * 1024 * 1024);     // 2.10 MB
  u16* sgu_b  = (u16*)alloc(2ull * 4096 * 1024);     // 8.39 MB (interleaved)
  u16* sdw_b  = (u16*)alloc(2ull * 1024 * 2048);     // 4.19 MB
  u16* w13_b  = (u16*)alloc(2ull * 8 * 2048 * 1024); // 33.6 MB (interleaved)
  u16* w2_b   = (u16*)alloc(2ull * 8 * 1024 * 1024); // 16.8 MB
  // region A: vbuf (8.4) -> eo (18.6)
  char* regA = (char*)alloc(2ull * Tc * 4096);
  // region B: h_b/kr/vt/qr (33.6); o_b reuses h_b slot; a13 reuses [0,18.6)
  char* regB = (char*)alloc(2ull * (size_t)MAX_TILES * 128 * 2048);
  float* x2  = (float*)alloc(4ull * Tc * Dc);        // 16.8 MB
  u16* hs_b  = (u16*)alloc(2ull * Tc * SH);          // 16.8 MB
  int* topk_e = (int*)alloc(2ull * Tc * 4);
  float* topk_w = (float*)alloc(2ull * Tc * 4);
  int* pos_of = (int*)alloc(2ull * Tc * 4);
  int* rowid = (int*)alloc(2ull * Tc * 4);
  int* etok = (int*)alloc(8ull * 4096 * 4);
  int* meta = (int*)alloc(512 * 4);

  u16* vbuf = (u16*)regA;                        // qkv V-third (8.4 MB)
  u16* eo_c = (u16*)regA;                        // w2 output (after vbuf dead)
  u16* h_b  = (u16*)regB;                        // mega_prep -> qkv gemm
  u16* kr   = (u16*)(regB + 2ull * Tc * Dc);
  u16* vt_  = (u16*)(regB + 4ull * Tc * Dc);
  u16* qr   = (u16*)(regB + 6ull * Tc * Dc);
  u16* o_b  = (u16*)regB;                        // attn out (h_b dead)
  u16* a13_c = (u16*)regB;                       // MoE compact (o_b dead)
  u16* hf_b = wqkv_b;  // overlays wqkv+wo after attention branch done

  // ---- prep: all converts + first rmsnorm in one dispatch ----
  mega_prep<<<dim3(21504), 256, 0, stream>>>(
      wq, wk, wv, wo, sdw, w2, sgw, suw, w1, w3, x, anw, wqkv_b, wo_b, sdw_b,
      w2_b, sgu_b, w13_b, h_b);

  // ---- attention branch ----
  // qkv GEMM with fused RoPE: q->qr, k->kr (rotated head-major), v->vbuf
  gemm_bt<10, 128, 1><<<dim3(3072 / 128, Tc / 128), 512, 0, stream>>>(
      h_b, wqkv_b, Tc, 3072, Dc, qr, (float*)kr, fc, fs,
      (const float*)vbuf, nullptr, nullptr);
  rope_v<<<dim3(Sc / 64, 2, 4), 256, 0, stream>>>(vbuf, vt_, Sc);
  attn_fwd<<<dim3(2 * NHc, Sc / 128), 256, 0, stream>>>(qr, kr, vt_, o_b, Sc,
                                                        NHc);
  gemm_bt<1, 64, 1><<<dim3(Dc / 128, Tc / 64), 512, 0, stream>>>(
      o_b, wo_b, Tc, Dc, Dc, nullptr, x2, x, nullptr, nullptr, nullptr,
      nullptr);

  // ---- ffn branch ----
  gate_topk<<<Tc / 4, 256, 0, stream>>>(x2, fnw, gw, gb, topk_e, topk_w,
                                        hf_b);
  route_tokens<<<1, 512, 0, stream>>>(topk_e, pos_of, etok, meta, rowid,
                                      2 * Tc);

  // merged: shared-expert gate|up (silu epilogue -> hs) + MoE w13 gather
  gemm_sgu_w13<<<dim3(1024 + 16 * MAX_TILES), 512, 0, stream>>>(
      hf_b, sgu_b, hs_b, w13_b, a13_c, b1, b3, meta, etok);

  // MoE w2 (TM=64 half-tiles)
  gemm_bt<6, 64><<<dim3(Dc / 128, 2 * MAX_TILES), 512, 0, stream>>>(
      a13_c, w2_b, /*lda=*/1024, Dc, 1024, eo_c, nullptr, nullptr, nullptr,
      b2, meta, etok);

  // final: out = x2 + hs @ sdw^T + w0*eo[r0] + w1*eo[r1]
  gemm_bt<9, 64, 1><<<dim3(Dc / 128, Tc / 64), 512, 0, stream>>>(
      hs_b, sdw_b, Tc, Dc, SH, eo_c, out, x2, nullptr, topk_w, rowid,
      nullptr);
}